// Round 1
// 505.566 us; speedup vs baseline: 1.1351x; 1.1351x over previous
//
#include <hip/hip_runtime.h>
#include <cstdint>

#define S_LEN 2048
#define EMB   2048
#define NHEAD 16
#define HDIM  128
#define NFUSE 2304   // fused proj width: 2048 q | 128 k | 128 v
#define LOG2E 1.4426950408889634f

typedef __attribute__((ext_vector_type(8))) short short8;
typedef __attribute__((ext_vector_type(4))) short short4v;
typedef __attribute__((ext_vector_type(4))) float f32x4;
typedef unsigned int u32;

// round-to-nearest-even float -> bf16 (finite inputs)
__device__ inline short f2bf(float x) {
  union { float f; uint32_t u; } v; v.f = x;
  uint32_t r = v.u + 0x7fffu + ((v.u >> 16) & 1u);
  return (short)(r >> 16);
}
__device__ inline float bf2f(short b) {
  union { uint32_t u; float f; } v; v.u = ((uint32_t)(uint16_t)b) << 16;
  return v.f;
}
// raw v_exp_f32 (2^x); inputs are pre-scaled to log2 domain
__device__ inline float fexp2(float x) {
  float r;
  __asm__ volatile("v_exp_f32 %0, %1" : "=v"(r) : "v"(x));
  return r;
}
// async global->LDS, 16B per lane; lds base must be wave-uniform
__device__ inline void glds16(const short* g, short* l) {
  __builtin_amdgcn_global_load_lds(
      (const __attribute__((address_space(1))) u32*)g,
      (__attribute__((address_space(3))) u32*)l, 16, 0, 0);
}

// ---------------------------------------------------------------------------
// W1 group-reduce -> Wkv f32 [2048][256] (k cols 0..127, v cols 128..255)
// ---------------------------------------------------------------------------
__global__ __launch_bounds__(256) void reduce_w1_kernel(
    const float* __restrict__ W1, float* __restrict__ Wkv) {
  int idx = blockIdx.x * 256 + threadIdx.x;
  int i = idx >> 8;
  int c = idx & 255;
  int base = (c < 128) ? c : (c + 384);
  const float* r = W1 + (size_t)i * 1024 + base;
  Wkv[idx] = (r[0] + r[128]) + (r[256] + r[384]);
}

// ---------------------------------------------------------------------------
// elementwise split f32 -> (hi, lo) bf16; 4 elements/thread
// ---------------------------------------------------------------------------
__global__ __launch_bounds__(256) void split_f32_kernel(
    const float* __restrict__ src, short* __restrict__ hi,
    short* __restrict__ lo) {
  size_t idx = (size_t)blockIdx.x * 256 + threadIdx.x;
  float4 v = *(const float4*)(src + idx * 4);
  float vv[4] = {v.x, v.y, v.z, v.w};
  short4v h4, l4;
#pragma unroll
  for (int j = 0; j < 4; ++j) {
    short h = f2bf(vv[j]);
    h4[j] = h;
    l4[j] = f2bf(vv[j] - bf2f(h));
  }
  *(short4v*)(hi + idx * 4) = h4;
  *(short4v*)(lo + idx * 4) = l4;
}

// ---------------------------------------------------------------------------
// tiled transpose + (optional split) f32 W[K][N] -> bf16 T[N][K]
// grid (N/64, K/64), 256 threads
// ---------------------------------------------------------------------------
template <bool SPLIT>
__global__ __launch_bounds__(256) void transpose_split_kernel(
    const float* __restrict__ W, short* __restrict__ Th,
    short* __restrict__ Tl, int K, int N) {
  __shared__ float T[64][65];
  const int tid = threadIdx.x;
  const int k0 = blockIdx.y * 64, n0 = blockIdx.x * 64;
  {
    int r = tid >> 2, c0 = (tid & 3) * 16;
    const float* src = W + (size_t)(k0 + r) * N + n0 + c0;
#pragma unroll
    for (int j = 0; j < 4; ++j) {
      float4 v = *(const float4*)(src + 4 * j);
      T[r][c0 + 4 * j + 0] = v.x; T[r][c0 + 4 * j + 1] = v.y;
      T[r][c0 + 4 * j + 2] = v.z; T[r][c0 + 4 * j + 3] = v.w;
    }
  }
  __syncthreads();
  {
    int n = tid >> 2, kc = (tid & 3) * 16;
    short8 h0, h1, l0, l1;
#pragma unroll
    for (int i = 0; i < 8; ++i) {
      float a = T[kc + i][n];
      float b = T[kc + 8 + i][n];
      short ha = f2bf(a), hb = f2bf(b);
      h0[i] = ha; h1[i] = hb;
      if (SPLIT) { l0[i] = f2bf(a - bf2f(ha)); l1[i] = f2bf(b - bf2f(hb)); }
    }
    size_t off = (size_t)(n0 + n) * K + k0 + kc;
    *(short8*)(Th + off) = h0;
    *(short8*)(Th + off + 8) = h1;
    if (SPLIT) {
      *(short8*)(Tl + off) = l0;
      *(short8*)(Tl + off + 8) = l1;
    }
  }
}

// ---------------------------------------------------------------------------
// MFMA GEMM: C[M][N] = A[M][K] @ B (Bt = B^T as [N][K] bf16).
// SPLIT: 3-term split-bf16 product, epilogue stores split bf16 (Chi,Clo),
//        scaled by log2e for cols < qlim (the Q columns).
// !SPLIT: plain bf16, f32 C out.
// 128x128 tile, BK=32, 4 waves; global_load_lds width-16 staging.
// ---------------------------------------------------------------------------
template <bool SPLIT>
__global__ __launch_bounds__(256, 2) void gemm_mfma(
    const short* __restrict__ Ah, const short* __restrict__ Al,
    const short* __restrict__ Bth, const short* __restrict__ Btl,
    float* __restrict__ C, short* __restrict__ Chi, short* __restrict__ Clo,
    int M, int N, int K, int qlim) {
  extern __shared__ short sm[];
  short* AhS = sm;            // [128][32]
  short* BhS = sm + 4096;
  short* AlS = sm + 8192;     // (SPLIT only)
  short* BlS = sm + 12288;

  const int tid  = threadIdx.x;
  const int w    = tid >> 6;
  const int lane = tid & 63;
  const int quad = lane >> 4, col16 = lane & 15;
  const int row0 = blockIdx.y * 128, col0 = blockIdx.x * 128;
  const float esc = (col0 < qlim) ? LOG2E : 1.0f;

  const int srow  = w * 32 + (lane >> 2);
  const int kpart = (lane & 3) * 8;
  const short* pAh0 = Ah + (size_t)(row0 + srow) * K + kpart;
  const short* pAh1 = pAh0 + (size_t)16 * K;
  const short* pBh0 = Bth + (size_t)(col0 + srow) * K + kpart;
  const short* pBh1 = pBh0 + (size_t)16 * K;
  const short* pAl0 = SPLIT ? Al + (size_t)(row0 + srow) * K + kpart : nullptr;
  const short* pAl1 = SPLIT ? pAl0 + (size_t)16 * K : nullptr;
  const short* pBl0 = SPLIT ? Btl + (size_t)(col0 + srow) * K + kpart : nullptr;
  const short* pBl1 = SPLIT ? pBl0 + (size_t)16 * K : nullptr;
  short* lA0 = AhS + (w * 32) * 32;
  short* lA1 = AhS + (w * 32 + 16) * 32;
  short* lB0 = BhS + (w * 32) * 32;
  short* lB1 = BhS + (w * 32 + 16) * 32;

  f32x4 acc[2][8];
#pragma unroll
  for (int mt = 0; mt < 2; ++mt)
#pragma unroll
    for (int nt = 0; nt < 8; ++nt) {
      acc[mt][nt][0] = 0.f; acc[mt][nt][1] = 0.f;
      acc[mt][nt][2] = 0.f; acc[mt][nt][3] = 0.f;
    }

  const int nchunk = K >> 5;
  for (int c = 0; c < nchunk; ++c) {
    glds16(pAh0, lA0); glds16(pAh1, lA1);
    glds16(pBh0, lB0); glds16(pBh1, lB1);
    if constexpr (SPLIT) {
      glds16(pAl0, AlS + (w * 32) * 32);
      glds16(pAl1, AlS + (w * 32 + 16) * 32);
      glds16(pBl0, BlS + (w * 32) * 32);
      glds16(pBl1, BlS + (w * 32 + 16) * 32);
    }
    pAh0 += 32; pAh1 += 32; pBh0 += 32; pBh1 += 32;
    if constexpr (SPLIT) { pAl0 += 32; pAl1 += 32; pBl0 += 32; pBl1 += 32; }
    __syncthreads();

    short8 afh[2], afl[2];
#pragma unroll
    for (int mt = 0; mt < 2; ++mt) {
      afh[mt] = *(const short8*)&AhS[(w * 32 + mt * 16 + col16) * 32 + quad * 8];
      if constexpr (SPLIT)
        afl[mt] = *(const short8*)&AlS[(w * 32 + mt * 16 + col16) * 32 + quad * 8];
    }
#pragma unroll
    for (int nt = 0; nt < 8; ++nt) {
      short8 bh = *(const short8*)&BhS[(nt * 16 + col16) * 32 + quad * 8];
      if constexpr (SPLIT) {
        short8 bl = *(const short8*)&BlS[(nt * 16 + col16) * 32 + quad * 8];
#pragma unroll
        for (int mt = 0; mt < 2; ++mt) {
          acc[mt][nt] = __builtin_amdgcn_mfma_f32_16x16x32_bf16(afh[mt], bh, acc[mt][nt], 0, 0, 0);
          acc[mt][nt] = __builtin_amdgcn_mfma_f32_16x16x32_bf16(afl[mt], bh, acc[mt][nt], 0, 0, 0);
          acc[mt][nt] = __builtin_amdgcn_mfma_f32_16x16x32_bf16(afh[mt], bl, acc[mt][nt], 0, 0, 0);
        }
      } else {
#pragma unroll
        for (int mt = 0; mt < 2; ++mt)
          acc[mt][nt] = __builtin_amdgcn_mfma_f32_16x16x32_bf16(afh[mt], bh, acc[mt][nt], 0, 0, 0);
      }
    }
    __syncthreads();
  }

#pragma unroll
  for (int mt = 0; mt < 2; ++mt)
#pragma unroll
    for (int nt = 0; nt < 8; ++nt)
#pragma unroll
      for (int r = 0; r < 4; ++r) {
        int row = row0 + w * 32 + mt * 16 + quad * 4 + r;
        int col = col0 + nt * 16 + col16;
        float v = acc[mt][nt][r];
        if constexpr (SPLIT) {
          v *= esc;
          short h = f2bf(v);
          size_t off = (size_t)row * N + col;
          Chi[off] = h;
          Clo[off] = f2bf(v - bf2f(h));
        } else {
          C[(size_t)row * N + col] = v;
        }
      }
}

// ---------------------------------------------------------------------------
// build VT bf16 [2][128][2048] from fused proj output cols 2176..2303 (v-hi)
// grid 64 blocks x 256 thr; block = 64 s-rows
// ---------------------------------------------------------------------------
__global__ __launch_bounds__(256) void build_vt(
    const short* __restrict__ QKh, short* __restrict__ VT) {
  __shared__ short T[64][136];
  const int tid = threadIdx.x;
  const int gs = blockIdx.x * 64;
  const int b = gs >> 11;
  const int s = gs & 2047;
  {
    int r = tid >> 2, c0 = (tid & 3) * 32;
    const short* src = QKh + (size_t)(gs + r) * NFUSE + 2176 + c0;
#pragma unroll
    for (int j = 0; j < 4; ++j)
      *(short8*)&T[r][c0 + 8 * j] = *(const short8*)(src + 8 * j);
  }
  __syncthreads();
  {
    int d = tid >> 1, c = (tid & 1) * 32;
    short* dst = VT + (size_t)(b * HDIM + d) * S_LEN + s + c;
#pragma unroll
    for (int jo = 0; jo < 4; ++jo) {
      short8 o;
#pragma unroll
      for (int i = 0; i < 8; ++i) o[i] = T[c + jo * 8 + i][d];
      *(short8*)(dst + jo * 8) = o;
    }
  }
}

// ---------------------------------------------------------------------------
// MFMA flash attention, BM=128 (2 Q-tiles per wave), BN=64, swapped operands.
//  * QK^T computed as mfma(K, Q)  -> S^T tile: lane owns Q-row col16.
//    Row softmax = 15 VALU max + 2 shuffles; mask loads are float4;
//    rescale/normalize are per-lane (no shuffles).
//  * PV computed as mfma(V^T, P^T) -> O^T tile, same lane->q mapping.
//  * All staging (Q prologue, K hi/lo, V) via global_load_lds with
//    granule-XOR-pre-swizzled source addresses; linear LDS; fragment
//    ds_read_b128 are bank-conflict-free.
//  * Pipeline: K_{i+1} issued after QK phase, V_{i+1} after PV phase,
//    mask after B1; loop-top counted s_waitcnt vmcnt(4). Queue = [K8,V4].
// grid (S/128, B*H), 256 threads = 4 waves. LDS = 64 KiB -> 2 blocks/CU.
// ---------------------------------------------------------------------------
__global__ __launch_bounds__(256, 2) void flash_mfma(
    const short* __restrict__ QKh, const short* __restrict__ QKl,
    const short* __restrict__ VT, const float* __restrict__ mask,
    short* __restrict__ AO) {
  __shared__ short KhS[64 * 128];        // 16 KiB, [64 s][128 d] swizzled
  __shared__ short KlS[64 * 128];        // 16 KiB
  __shared__ short VtS[128 * 64];        // 16 KiB, [128 d][64 s] swizzled
  __shared__ short PsS[2 * 4 * 16 * 64]; // 16 KiB, [tile][wave][16 q][64 s]

  const int tid   = threadIdx.x;
  const int w     = tid >> 6;
  const int lane  = tid & 63;
  const int quad  = lane >> 4;
  const int col16 = lane & 15;
  const int xq    = col16 & 7;
  const int bh = blockIdx.y, b = bh >> 4, h = bh & 15;
  const int t0 = blockIdx.x * 128;

  const int jr = lane >> 4;   // K/Q staging: row-within-instr 0..3
  const int kg = lane & 15;   // K/Q staging: dest granule (16B units)
  const int vr = lane >> 3;   // V staging: row-within-instr 0..7
  const int vg = lane & 7;    // V staging: dest granule

  short* myK  = KhS + w * 2048;   // wave staging region: 16 rows x 128
  short* myKl = KlS + w * 2048;
  short* myV  = VtS + w * 2048;   // wave staging region: 32 d-rows x 64

  // ---- Q prologue: wave-local glds staging + fragment extraction
  short8 qfh[2][4], qfl[2][4];
#pragma unroll
  for (int t = 0; t < 2; ++t) {
#pragma unroll
    for (int j = 0; j < 4; ++j) {
      int rl = 4 * j + jr;
      int gq = kg ^ (rl & 7);
      size_t go = (size_t)(b * S_LEN + t0 + 64 * t + 16 * w + rl) * NFUSE
                + h * HDIM + gq * 8;
      glds16(QKh + go, myK + j * 512);
      glds16(QKl + go, myKl + j * 512);
    }
    __asm__ volatile("s_waitcnt vmcnt(0)" ::: "memory");
#pragma unroll
    for (int c = 0; c < 4; ++c) {
      int off = col16 * 128 + (((c * 4 + quad) ^ xq) * 8);
      qfh[t][c] = *(const short8*)&myK[off];
      qfl[t][c] = *(const short8*)&myKl[off];
    }
    __asm__ volatile("s_waitcnt lgkmcnt(0)" ::: "memory");  // reads retired
  }

  // ---- per-lane staging offsets (source swizzled; LDS linear)
  size_t offK[4], offV[4];
#pragma unroll
  for (int j = 0; j < 4; ++j) {
    int rl = 4 * j + jr;
    offK[j] = (size_t)(b * S_LEN + 16 * w + rl) * NFUSE + 2048
            + (size_t)((kg ^ (rl & 7)) * 8);
    int dl = 32 * w + 8 * j + vr;
    offV[j] = (size_t)(b * HDIM + dl) * S_LEN + (size_t)((vg ^ (vr & 7)) * 8);
  }
  const float* pM[2];
#pragma unroll
  for (int t = 0; t < 2; ++t)
    pM[t] = mask + (size_t)b * S_LEN * S_LEN
          + (size_t)(t0 + 64 * t + 16 * w + col16) * S_LEN + quad * 4;

  // ---- issue K_0 then V_0 (queue discipline: [K8, V4])
#pragma unroll
  for (int j = 0; j < 4; ++j) glds16(QKh + offK[j], myK + j * 512);
#pragma unroll
  for (int j = 0; j < 4; ++j) glds16(QKl + offK[j], myKl + j * 512);
#pragma unroll
  for (int j = 0; j < 4; ++j) glds16(VT + offV[j], myV + j * 512);
#pragma unroll
  for (int j = 0; j < 4; ++j) { offK[j] += (size_t)64 * NFUSE; offV[j] += 64; }

  f32x4 oacc[2][8];
#pragma unroll
  for (int t = 0; t < 2; ++t)
#pragma unroll
    for (int d = 0; d < 8; ++d) {
      oacc[t][d][0] = 0.f; oacc[t][d][1] = 0.f;
      oacc[t][d][2] = 0.f; oacc[t][d][3] = 0.f;
    }
  float mrow[2] = {-3.0e38f, -3.0e38f};
  float lrow[2] = {0.f, 0.f};

#pragma unroll 1
  for (int it = 0; it < S_LEN / 64; ++it) {
    // ---- B1: K_it arrived on all waves (V_it still in flight)
    __asm__ volatile("s_waitcnt vmcnt(4)" ::: "memory");
    __builtin_amdgcn_s_barrier();

    // mask for this tile (float4 per nt), flies under QK MFMAs
    float4 mreg[2][4];
#pragma unroll
    for (int t = 0; t < 2; ++t)
#pragma unroll
      for (int nt = 0; nt < 4; ++nt)
        mreg[t][nt] = *(const float4*)(pM[t] + nt * 16);

    // ---- QK^T swapped: sacc[t][nt] = S^T (rows = s-local, cols = q)
    f32x4 sacc[2][4];
#pragma unroll
    for (int t = 0; t < 2; ++t)
#pragma unroll
      for (int nt = 0; nt < 4; ++nt) {
        sacc[t][nt][0] = 0.f; sacc[t][nt][1] = 0.f;
        sacc[t][nt][2] = 0.f; sacc[t][nt][3] = 0.f;
      }
#pragma unroll
    for (int c = 0; c < 4; ++c)
#pragma unroll
      for (int nt = 0; nt < 4; ++nt) {
        int off = (nt * 16 + col16) * 128 + (((c * 4 + quad) ^ xq) * 8);
        short8 kh8 = *(const short8*)&KhS[off];
        short8 kl8 = *(const short8*)&KlS[off];
#pragma unroll
        for (int t = 0; t < 2; ++t) {
          sacc[t][nt] = __builtin_amdgcn_mfma_f32_16x16x32_bf16(kh8, qfh[t][c], sacc[t][nt], 0, 0, 0);
          sacc[t][nt] = __builtin_amdgcn_mfma_f32_16x16x32_bf16(kh8, qfl[t][c], sacc[t][nt], 0, 0, 0);
          sacc[t][nt] = __builtin_amdgcn_mfma_f32_16x16x32_bf16(kl8, qfh[t][c], sacc[t][nt], 0, 0, 0);
        }
      }

    // ---- B2: K-buf free on all waves; V_it (and mask) drained
    __asm__ volatile("s_waitcnt vmcnt(0)" ::: "memory");
    __builtin_amdgcn_s_barrier();

    if (it + 1 < S_LEN / 64) {   // prefetch K_{it+1}, flies under softmax+PV
#pragma unroll
      for (int j = 0; j < 4; ++j) glds16(QKh + offK[j], myK + j * 512);
#pragma unroll
      for (int j = 0; j < 4; ++j) glds16(QKl + offK[j], myKl + j * 512);
#pragma unroll
      for (int j = 0; j < 4; ++j) offK[j] += (size_t)64 * NFUSE;
    }

    // ---- online softmax (base-2), per tile; lane owns Q-row col16
#pragma unroll
    for (int t = 0; t < 2; ++t) {
      float vv[4][4];
#pragma unroll
      for (int nt = 0; nt < 4; ++nt) {
        vv[nt][0] = fmaf(mreg[t][nt].x, LOG2E, sacc[t][nt][0]);
        vv[nt][1] = fmaf(mreg[t][nt].y, LOG2E, sacc[t][nt][1]);
        vv[nt][2] = fmaf(mreg[t][nt].z, LOG2E, sacc[t][nt][2]);
        vv[nt][3] = fmaf(mreg[t][nt].w, LOG2E, sacc[t][nt][3]);
      }
      float mx = vv[0][0];
#pragma unroll
      for (int nt = 0; nt < 4; ++nt)
#pragma unroll
        for (int r = 0; r < 4; ++r) mx = fmaxf(mx, vv[nt][r]);
      mx = fmaxf(mx, __shfl_xor(mx, 16));
      mx = fmaxf(mx, __shfl_xor(mx, 32));
      float nm = fmaxf(mrow[t], mx);

      float ps = 0.f;
      u32 pk0[4], pk1[4];
#pragma unroll
      for (int nt = 0; nt < 4; ++nt) {
        union { float f; u32 u; } p0, p1, p2, p3, q0, q1, q2, q3;
        p0.f = fexp2(vv[nt][0] - nm);
        p1.f = fexp2(vv[nt][1] - nm);
        p2.f = fexp2(vv[nt][2] - nm);
        p3.f = fexp2(vv[nt][3] - nm);
        // truncate to bf16; sum the truncated values so num/denom cancel
        q0.u = p0.u & 0xffff0000u; q1.u = p1.u & 0xffff0000u;
        q2.u = p2.u & 0xffff0000u; q3.u = p3.u & 0xffff0000u;
        ps += (q0.f + q1.f) + (q2.f + q3.f);
        pk0[nt] = (p0.u >> 16) | (p1.u & 0xffff0000u);
        pk1[nt] = (p2.u >> 16) | (p3.u & 0xffff0000u);
      }
      ps += __shfl_xor(ps, 16);
      ps += __shfl_xor(ps, 32);
      float al = fexp2(mrow[t] - nm);
      lrow[t] = lrow[t] * al + ps;
      mrow[t] = nm;

      // P store: 4x b64, granule-XOR swizzled, conflict-free
      int pbase = ((t * 4 + w) * 16 + col16) * 64 + (quad & 1) * 4;
#pragma unroll
      for (int nt = 0; nt < 4; ++nt) {
        uint2 pv2; pv2.x = pk0[nt]; pv2.y = pk1[nt];
        *(uint2*)&PsS[pbase + (((2 * nt + (quad >> 1)) ^ xq) * 8)] = pv2;
      }
      // O rescale: per-lane (all rows of oacc[t] share q = col16)
#pragma unroll
      for (int d = 0; d < 8; ++d) {
        oacc[t][d][0] *= al; oacc[t][d][1] *= al;
        oacc[t][d][2] *= al; oacc[t][d][3] *= al;
      }
    }

    // ---- PV swapped: oacc[t][d] += mfma(V^T-frag, P^T-frag)
    __asm__ volatile("s_waitcnt lgkmcnt(0)" ::: "memory");  // P visible in-wave
    short8 pa[2][2];
#pragma unroll
    for (int t = 0; t < 2; ++t) {
      int pb = ((t * 4 + w) * 16 + col16) * 64;
      pa[t][0] = *(const short8*)&PsS[pb + ((quad ^ xq) * 8)];
      pa[t][1] = *(const short8*)&PsS[pb + (((4 + quad) ^ xq) * 8)];
    }
#pragma unroll
    for (int d = 0; d < 8; ++d) {
      int vo = (d * 16 + col16) * 64;
      short8 vb0 = *(const short8*)&VtS[vo + ((quad ^ xq) * 8)];
      short8 vb1 = *(const short8*)&VtS[vo + (((4 + quad) ^ xq) * 8)];
#pragma unroll
      for (int t = 0; t < 2; ++t) {
        oacc[t][d] = __builtin_amdgcn_mfma_f32_16x16x32_bf16(vb0, pa[t][0], oacc[t][d], 0, 0, 0);
        oacc[t][d] = __builtin_amdgcn_mfma_f32_16x16x32_bf16(vb1, pa[t][1], oacc[t][d], 0, 0, 0);
      }
    }

    // ---- B3: V-buf free on all waves; prefetch V_{it+1} (flies under next QK)
    __builtin_amdgcn_s_barrier();
    if (it + 1 < S_LEN / 64) {
#pragma unroll
      for (int j = 0; j < 4; ++j) glds16(VT + offV[j], myV + j * 512);
#pragma unroll
      for (int j = 0; j < 4; ++j) offV[j] += 64;
    }
#pragma unroll
    for (int t = 0; t < 2; ++t) pM[t] += 64;
  }

  // ---- epilogue: normalize, packed b64 stores, AO bf16 [4096][2048]
#pragma unroll
  for (int t = 0; t < 2; ++t) {
    float inv = 1.0f / lrow[t];
    int q = t0 + 64 * t + 16 * w + col16;
    short* dst = AO + (size_t)(b * S_LEN + q) * EMB + h * HDIM + quad * 4;
#pragma unroll
    for (int d = 0; d < 8; ++d) {
      short4v o4;
#pragma unroll
      for (int r = 0; r < 4; ++r) o4[r] = f2bf(oacc[t][d][r] * inv);
      *(short4v*)(dst + d * 16) = o4;
    }
  }
}

// ---------------------------------------------------------------------------
extern "C" void kernel_launch(void* const* d_in, const int* in_sizes, int n_in,
                              void* d_out, int out_size, void* d_ws, size_t ws_size,
                              hipStream_t stream) {
  const float* x    = (const float*)d_in[0];
  const float* mask = (const float*)d_in[1];
  const float* W1   = (const float*)d_in[2];
  const float* W2   = (const float*)d_in[3];
  const float* W3   = (const float*)d_in[4];
  float* out = (float*)d_out;

  char* ws = (char*)d_ws;
  size_t off = 0;
  short* xh   = (short*)(ws + off); off += (size_t)4096 * 2048 * 2;   // 16 MiB
  short* xl   = (short*)(ws + off); off += (size_t)4096 * 2048 * 2;   // 16 MiB
  short* Wth  = (short*)(ws + off); off += (size_t)NFUSE * 2048 * 2;  //  9 MiB
  short* Wtl  = (short*)(ws + off); off += (size_t)NFUSE * 2048 * 2;  //  9 MiB
  short* QKh  = (short*)(ws + off); off += (size_t)4096 * NFUSE * 2;  // 18 MiB
  short* QKl  = (short*)(ws + off); off += (size_t)4096 * NFUSE * 2;  // 18 MiB
  short* VT   = (short*)(ws + off); off += (size_t)2 * 128 * 2048 * 2;//  1 MiB
  short* AObf = (short*)(ws + off); off += (size_t)4096 * 2048 * 2;   // 16 MiB
  float* Wkv  = (float*)(ws + off); off += (size_t)2048 * 256 * 4;    //  2 MiB
  short* W3t  = xh;  // alias: xh dead after fused GEMM; W3 transpose runs after

  // 1) prep: Wkv reduce, x split, fused W^T split (W2 rows 0..2047, Wkv rows 2048..2303)
  reduce_w1_kernel<<<2048, 256, 0, stream>>>(W1, Wkv);
  split_f32_kernel<<<8192, 256, 0, stream>>>(x, xh, xl);
  transpose_split_kernel<true><<<dim3(32, 32), 256, 0, stream>>>(W2, Wth, Wtl, 2048, 2048);
  transpose_split_kernel<true><<<dim3(4, 32), 256, 0, stream>>>(
      Wkv, Wth + (size_t)2048 * 2048, Wtl + (size_t)2048 * 2048, 2048, 256);

  // 2) fused projection GEMM: [4096][2304] = x @ [W2 | Wk | Wv], split output,
  //    Q cols pre-scaled by log2e
  gemm_mfma<true><<<dim3(NFUSE / 128, 32), 256, 32768, stream>>>(
      xh, xl, Wth, Wtl, nullptr, QKh, QKl, 4096, NFUSE, 2048, 2048);

  // 3) V^T extraction
  build_vt<<<64, 256, 0, stream>>>(QKh, VT);

  // 4) attention
  flash_mfma<<<dim3(S_LEN / 128, 2 * NHEAD), 256, 0, stream>>>(
      QKh, QKl, VT, mask, AObf);

  // 5) output projection (plain bf16)
  transpose_split_kernel<false><<<dim3(32, 32), 256, 0, stream>>>(W3, W3t, nullptr, 2048, 2048);
  gemm_mfma<false><<<dim3(16, 32), 256, 16384, stream>>>(
      AObf, nullptr, W3t, nullptr, out, nullptr, nullptr, 4096, 2048, 2048, 0);
}

// Round 2
// 494.857 us; speedup vs baseline: 1.1597x; 1.0216x over previous
//
#include <hip/hip_runtime.h>
#include <cstdint>

#define S_LEN 2048
#define EMB   2048
#define NHEAD 16
#define HDIM  128
#define NFUSE 2304   // fused proj width: 2048 q | 128 k | 128 v
#define LOG2E 1.4426950408889634f

typedef __attribute__((ext_vector_type(8))) short short8;
typedef __attribute__((ext_vector_type(4))) short short4v;
typedef __attribute__((ext_vector_type(4))) float f32x4;
typedef unsigned int u32;

// round-to-nearest-even float -> bf16 (finite inputs)
__device__ inline short f2bf(float x) {
  union { float f; uint32_t u; } v; v.f = x;
  uint32_t r = v.u + 0x7fffu + ((v.u >> 16) & 1u);
  return (short)(r >> 16);
}
__device__ inline float bf2f(short b) {
  union { uint32_t u; float f; } v; v.u = ((uint32_t)(uint16_t)b) << 16;
  return v.f;
}
// raw v_exp_f32 (2^x); inputs are pre-scaled to log2 domain
__device__ inline float fexp2(float x) {
  float r;
  __asm__ volatile("v_exp_f32 %0, %1" : "=v"(r) : "v"(x));
  return r;
}
// async global->LDS, 16B per lane; lds base must be wave-uniform
__device__ inline void glds16(const short* g, short* l) {
  __builtin_amdgcn_global_load_lds(
      (const __attribute__((address_space(1))) u32*)g,
      (__attribute__((address_space(3))) u32*)l, 16, 0, 0);
}

// ---------------------------------------------------------------------------
// W1 group-reduce -> Wkv f32 [2048][256] (k cols 0..127, v cols 128..255)
// ---------------------------------------------------------------------------
__global__ __launch_bounds__(256) void reduce_w1_kernel(
    const float* __restrict__ W1, float* __restrict__ Wkv) {
  int idx = blockIdx.x * 256 + threadIdx.x;
  int i = idx >> 8;
  int c = idx & 255;
  int base = (c < 128) ? c : (c + 384);
  const float* r = W1 + (size_t)i * 1024 + base;
  Wkv[idx] = (r[0] + r[128]) + (r[256] + r[384]);
}

// ---------------------------------------------------------------------------
// elementwise split f32 -> (hi, lo) bf16; 4 elements/thread
// ---------------------------------------------------------------------------
__global__ __launch_bounds__(256) void split_f32_kernel(
    const float* __restrict__ src, short* __restrict__ hi,
    short* __restrict__ lo) {
  size_t idx = (size_t)blockIdx.x * 256 + threadIdx.x;
  float4 v = *(const float4*)(src + idx * 4);
  float vv[4] = {v.x, v.y, v.z, v.w};
  short4v h4, l4;
#pragma unroll
  for (int j = 0; j < 4; ++j) {
    short h = f2bf(vv[j]);
    h4[j] = h;
    l4[j] = f2bf(vv[j] - bf2f(h));
  }
  *(short4v*)(hi + idx * 4) = h4;
  *(short4v*)(lo + idx * 4) = l4;
}

// ---------------------------------------------------------------------------
// tiled transpose + (optional split) f32 W[K][N] -> bf16 T[N][K]
// grid (N/64, K/64), 256 threads
// ---------------------------------------------------------------------------
template <bool SPLIT>
__global__ __launch_bounds__(256) void transpose_split_kernel(
    const float* __restrict__ W, short* __restrict__ Th,
    short* __restrict__ Tl, int K, int N) {
  __shared__ float T[64][65];
  const int tid = threadIdx.x;
  const int k0 = blockIdx.y * 64, n0 = blockIdx.x * 64;
  {
    int r = tid >> 2, c0 = (tid & 3) * 16;
    const float* src = W + (size_t)(k0 + r) * N + n0 + c0;
#pragma unroll
    for (int j = 0; j < 4; ++j) {
      float4 v = *(const float4*)(src + 4 * j);
      T[r][c0 + 4 * j + 0] = v.x; T[r][c0 + 4 * j + 1] = v.y;
      T[r][c0 + 4 * j + 2] = v.z; T[r][c0 + 4 * j + 3] = v.w;
    }
  }
  __syncthreads();
  {
    int n = tid >> 2, kc = (tid & 3) * 16;
    short8 h0, h1, l0, l1;
#pragma unroll
    for (int i = 0; i < 8; ++i) {
      float a = T[kc + i][n];
      float b = T[kc + 8 + i][n];
      short ha = f2bf(a), hb = f2bf(b);
      h0[i] = ha; h1[i] = hb;
      if (SPLIT) { l0[i] = f2bf(a - bf2f(ha)); l1[i] = f2bf(b - bf2f(hb)); }
    }
    size_t off = (size_t)(n0 + n) * K + k0 + kc;
    *(short8*)(Th + off) = h0;
    *(short8*)(Th + off + 8) = h1;
    if (SPLIT) {
      *(short8*)(Tl + off) = l0;
      *(short8*)(Tl + off + 8) = l1;
    }
  }
}

// ---------------------------------------------------------------------------
// MFMA GEMM: C[M][N] = A[M][K] @ B (Bt = B^T as [N][K] bf16).
// SPLIT: 3-term split-bf16 product, epilogue stores split bf16 (Chi,Clo),
//        scaled by log2e for cols < qlim (the Q columns).
// !SPLIT: plain bf16, f32 C out.
// 128x128 tile, BK=32, 4 waves; double-buffered LDS, global_load_lds
// width-16 staging, counted s_waitcnt vmcnt(N) so the next tile's loads
// stay in flight across the barrier (T3 2-phase + T4).
// LDS: SPLIT 2x32 KiB, plain 2x16 KiB.
// ---------------------------------------------------------------------------
template <bool SPLIT>
__global__ __launch_bounds__(256, 2) void gemm_mfma(
    const short* __restrict__ Ah, const short* __restrict__ Al,
    const short* __restrict__ Bth, const short* __restrict__ Btl,
    float* __restrict__ C, short* __restrict__ Chi, short* __restrict__ Clo,
    int M, int N, int K, int qlim) {
  extern __shared__ short sm[];
  constexpr int BUFS = SPLIT ? 16384 : 8192;  // shorts per buffer

  const int tid  = threadIdx.x;
  const int w    = tid >> 6;
  const int lane = tid & 63;
  const int quad = lane >> 4, col16 = lane & 15;
  const int row0 = blockIdx.y * 128, col0 = blockIdx.x * 128;
  const float esc = (col0 < qlim) ? LOG2E : 1.0f;

  const int srow  = w * 32 + (lane >> 2);
  const int kpart = (lane & 3) * 8;
  const short* pAh0 = Ah + (size_t)(row0 + srow) * K + kpart;
  const short* pAh1 = pAh0 + (size_t)16 * K;
  const short* pBh0 = Bth + (size_t)(col0 + srow) * K + kpart;
  const short* pBh1 = pBh0 + (size_t)16 * K;
  const short* pAl0 = SPLIT ? Al + (size_t)(row0 + srow) * K + kpart : nullptr;
  const short* pAl1 = SPLIT ? pAl0 + (size_t)16 * K : nullptr;
  const short* pBl0 = SPLIT ? Btl + (size_t)(col0 + srow) * K + kpart : nullptr;
  const short* pBl1 = SPLIT ? pBl0 + (size_t)16 * K : nullptr;

  // wave-local staging offsets within a buffer (Ah +0, Bh +4096, lo = +8192)
  const int oA0 = (w * 32) * 32, oA1 = (w * 32 + 16) * 32;
  const int oB0 = 4096 + (w * 32) * 32, oB1 = 4096 + (w * 32 + 16) * 32;

#define STAGE_GEMM(bo)                                                        \
  do {                                                                        \
    glds16(pAh0, sm + (bo) + oA0); glds16(pAh1, sm + (bo) + oA1);             \
    glds16(pBh0, sm + (bo) + oB0); glds16(pBh1, sm + (bo) + oB1);             \
    if constexpr (SPLIT) {                                                    \
      glds16(pAl0, sm + (bo) + 8192 + oA0);                                   \
      glds16(pAl1, sm + (bo) + 8192 + oA1);                                   \
      glds16(pBl0, sm + (bo) + 8192 + oB0);                                   \
      glds16(pBl1, sm + (bo) + 8192 + oB1);                                   \
    }                                                                         \
    pAh0 += 32; pAh1 += 32; pBh0 += 32; pBh1 += 32;                           \
    if constexpr (SPLIT) { pAl0 += 32; pAl1 += 32; pBl0 += 32; pBl1 += 32; }  \
  } while (0)

  f32x4 acc[2][8];
#pragma unroll
  for (int mt = 0; mt < 2; ++mt)
#pragma unroll
    for (int nt = 0; nt < 8; ++nt) {
      acc[mt][nt][0] = 0.f; acc[mt][nt][1] = 0.f;
      acc[mt][nt][2] = 0.f; acc[mt][nt][3] = 0.f;
    }

  const int nchunk = K >> 5;
  int bo = 0;
  STAGE_GEMM(0);                       // prologue: tile 0 in flight

#pragma unroll 1
  for (int c = 0; c < nchunk; ++c) {
    if (c + 1 < nchunk) {
      STAGE_GEMM(bo ^ BUFS);           // issue tile c+1 (flies under MFMA)
      if constexpr (SPLIT) {
        __asm__ volatile("s_waitcnt vmcnt(8)" ::: "memory");
      } else {
        __asm__ volatile("s_waitcnt vmcnt(4)" ::: "memory");
      }
    } else {
      __asm__ volatile("s_waitcnt vmcnt(0)" ::: "memory");
    }
    __builtin_amdgcn_s_barrier();      // tile c resident on all waves

    const short* AhS = sm + bo;
    const short* BhS = sm + bo + 4096;
    const short* AlS = sm + bo + 8192;
    const short* BlS = sm + bo + 12288;

    short8 afh[2], afl[2];
#pragma unroll
    for (int mt = 0; mt < 2; ++mt) {
      afh[mt] = *(const short8*)&AhS[(w * 32 + mt * 16 + col16) * 32 + quad * 8];
      if constexpr (SPLIT)
        afl[mt] = *(const short8*)&AlS[(w * 32 + mt * 16 + col16) * 32 + quad * 8];
    }
#pragma unroll
    for (int nt = 0; nt < 8; ++nt) {
      short8 bh = *(const short8*)&BhS[(nt * 16 + col16) * 32 + quad * 8];
      if constexpr (SPLIT) {
        short8 bl = *(const short8*)&BlS[(nt * 16 + col16) * 32 + quad * 8];
#pragma unroll
        for (int mt = 0; mt < 2; ++mt) {
          acc[mt][nt] = __builtin_amdgcn_mfma_f32_16x16x32_bf16(afh[mt], bh, acc[mt][nt], 0, 0, 0);
          acc[mt][nt] = __builtin_amdgcn_mfma_f32_16x16x32_bf16(afl[mt], bh, acc[mt][nt], 0, 0, 0);
          acc[mt][nt] = __builtin_amdgcn_mfma_f32_16x16x32_bf16(afh[mt], bl, acc[mt][nt], 0, 0, 0);
        }
      } else {
#pragma unroll
        for (int mt = 0; mt < 2; ++mt)
          acc[mt][nt] = __builtin_amdgcn_mfma_f32_16x16x32_bf16(afh[mt], bh, acc[mt][nt], 0, 0, 0);
      }
    }
    __builtin_amdgcn_s_barrier();      // all reads of tile c done (ds_reads
    bo ^= BUFS;                        // retired before their MFMAs issued)
  }
#undef STAGE_GEMM

#pragma unroll
  for (int mt = 0; mt < 2; ++mt)
#pragma unroll
    for (int nt = 0; nt < 8; ++nt)
#pragma unroll
      for (int r = 0; r < 4; ++r) {
        int row = row0 + w * 32 + mt * 16 + quad * 4 + r;
        int col = col0 + nt * 16 + col16;
        float v = acc[mt][nt][r];
        if constexpr (SPLIT) {
          v *= esc;
          short h = f2bf(v);
          size_t off = (size_t)row * N + col;
          Chi[off] = h;
          Clo[off] = f2bf(v - bf2f(h));
        } else {
          C[(size_t)row * N + col] = v;
        }
      }
}

// ---------------------------------------------------------------------------
// build VT bf16 [2][128][2048] from fused proj output cols 2176..2303 (v-hi)
// grid 64 blocks x 256 thr; block = 64 s-rows
// ---------------------------------------------------------------------------
__global__ __launch_bounds__(256) void build_vt(
    const short* __restrict__ QKh, short* __restrict__ VT) {
  __shared__ short T[64][136];
  const int tid = threadIdx.x;
  const int gs = blockIdx.x * 64;
  const int b = gs >> 11;
  const int s = gs & 2047;
  {
    int r = tid >> 2, c0 = (tid & 3) * 32;
    const short* src = QKh + (size_t)(gs + r) * NFUSE + 2176 + c0;
#pragma unroll
    for (int j = 0; j < 4; ++j)
      *(short8*)&T[r][c0 + 8 * j] = *(const short8*)(src + 8 * j);
  }
  __syncthreads();
  {
    int d = tid >> 1, c = (tid & 1) * 32;
    short* dst = VT + (size_t)(b * HDIM + d) * S_LEN + s + c;
#pragma unroll
    for (int jo = 0; jo < 4; ++jo) {
      short8 o;
#pragma unroll
      for (int i = 0; i < 8; ++i) o[i] = T[c + jo * 8 + i][d];
      *(short8*)(dst + jo * 8) = o;
    }
  }
}

// ---------------------------------------------------------------------------
// MFMA flash attention, BM=128 (2 Q-tiles per wave), BN=64, swapped operands.
//  * QK^T computed as mfma(K, Q)  -> S^T tile: lane owns Q-row col16.
//  * PV computed as mfma(V^T, P^T) -> O^T tile, same lane->q mapping.
//  * All staging via global_load_lds, granule-XOR-pre-swizzled source.
//  * Pipeline: K_{i+1} issued after QK phase, V_{i+1} after PV phase,
//    mask after B1; loop-top counted s_waitcnt vmcnt(4). Queue = [K8,V4].
//  * s_setprio(1) around the QK and PV MFMA clusters (T5).
// grid (S/128, B*H), 256 threads = 4 waves. LDS = 64 KiB -> 2 blocks/CU.
// ---------------------------------------------------------------------------
__global__ __launch_bounds__(256, 2) void flash_mfma(
    const short* __restrict__ QKh, const short* __restrict__ QKl,
    const short* __restrict__ VT, const float* __restrict__ mask,
    short* __restrict__ AO) {
  __shared__ short KhS[64 * 128];        // 16 KiB, [64 s][128 d] swizzled
  __shared__ short KlS[64 * 128];        // 16 KiB
  __shared__ short VtS[128 * 64];        // 16 KiB, [128 d][64 s] swizzled
  __shared__ short PsS[2 * 4 * 16 * 64]; // 16 KiB, [tile][wave][16 q][64 s]

  const int tid   = threadIdx.x;
  const int w     = tid >> 6;
  const int lane  = tid & 63;
  const int quad  = lane >> 4;
  const int col16 = lane & 15;
  const int xq    = col16 & 7;
  const int bh = blockIdx.y, b = bh >> 4, h = bh & 15;
  const int t0 = blockIdx.x * 128;

  const int jr = lane >> 4;   // K/Q staging: row-within-instr 0..3
  const int kg = lane & 15;   // K/Q staging: dest granule (16B units)
  const int vr = lane >> 3;   // V staging: row-within-instr 0..7
  const int vg = lane & 7;    // V staging: dest granule

  short* myK  = KhS + w * 2048;   // wave staging region: 16 rows x 128
  short* myKl = KlS + w * 2048;
  short* myV  = VtS + w * 2048;   // wave staging region: 32 d-rows x 64

  // ---- Q prologue: wave-local glds staging + fragment extraction
  short8 qfh[2][4], qfl[2][4];
#pragma unroll
  for (int t = 0; t < 2; ++t) {
#pragma unroll
    for (int j = 0; j < 4; ++j) {
      int rl = 4 * j + jr;
      int gq = kg ^ (rl & 7);
      size_t go = (size_t)(b * S_LEN + t0 + 64 * t + 16 * w + rl) * NFUSE
                + h * HDIM + gq * 8;
      glds16(QKh + go, myK + j * 512);
      glds16(QKl + go, myKl + j * 512);
    }
    __asm__ volatile("s_waitcnt vmcnt(0)" ::: "memory");
#pragma unroll
    for (int c = 0; c < 4; ++c) {
      int off = col16 * 128 + (((c * 4 + quad) ^ xq) * 8);
      qfh[t][c] = *(const short8*)&myK[off];
      qfl[t][c] = *(const short8*)&myKl[off];
    }
    __asm__ volatile("s_waitcnt lgkmcnt(0)" ::: "memory");  // reads retired
  }

  // ---- per-lane staging offsets (source swizzled; LDS linear)
  size_t offK[4], offV[4];
#pragma unroll
  for (int j = 0; j < 4; ++j) {
    int rl = 4 * j + jr;
    offK[j] = (size_t)(b * S_LEN + 16 * w + rl) * NFUSE + 2048
            + (size_t)((kg ^ (rl & 7)) * 8);
    int dl = 32 * w + 8 * j + vr;
    offV[j] = (size_t)(b * HDIM + dl) * S_LEN + (size_t)((vg ^ (vr & 7)) * 8);
  }
  const float* pM[2];
#pragma unroll
  for (int t = 0; t < 2; ++t)
    pM[t] = mask + (size_t)b * S_LEN * S_LEN
          + (size_t)(t0 + 64 * t + 16 * w + col16) * S_LEN + quad * 4;

  // ---- issue K_0 then V_0 (queue discipline: [K8, V4])
#pragma unroll
  for (int j = 0; j < 4; ++j) glds16(QKh + offK[j], myK + j * 512);
#pragma unroll
  for (int j = 0; j < 4; ++j) glds16(QKl + offK[j], myKl + j * 512);
#pragma unroll
  for (int j = 0; j < 4; ++j) glds16(VT + offV[j], myV + j * 512);
#pragma unroll
  for (int j = 0; j < 4; ++j) { offK[j] += (size_t)64 * NFUSE; offV[j] += 64; }

  f32x4 oacc[2][8];
#pragma unroll
  for (int t = 0; t < 2; ++t)
#pragma unroll
    for (int d = 0; d < 8; ++d) {
      oacc[t][d][0] = 0.f; oacc[t][d][1] = 0.f;
      oacc[t][d][2] = 0.f; oacc[t][d][3] = 0.f;
    }
  float mrow[2] = {-3.0e38f, -3.0e38f};
  float lrow[2] = {0.f, 0.f};

#pragma unroll 1
  for (int it = 0; it < S_LEN / 64; ++it) {
    // ---- B1: K_it arrived on all waves (V_it still in flight)
    __asm__ volatile("s_waitcnt vmcnt(4)" ::: "memory");
    __builtin_amdgcn_s_barrier();

    // mask for this tile (float4 per nt), flies under QK MFMAs
    float4 mreg[2][4];
#pragma unroll
    for (int t = 0; t < 2; ++t)
#pragma unroll
      for (int nt = 0; nt < 4; ++nt)
        mreg[t][nt] = *(const float4*)(pM[t] + nt * 16);

    // ---- QK^T swapped: sacc[t][nt] = S^T (rows = s-local, cols = q)
    f32x4 sacc[2][4];
#pragma unroll
    for (int t = 0; t < 2; ++t)
#pragma unroll
      for (int nt = 0; nt < 4; ++nt) {
        sacc[t][nt][0] = 0.f; sacc[t][nt][1] = 0.f;
        sacc[t][nt][2] = 0.f; sacc[t][nt][3] = 0.f;
      }
    __builtin_amdgcn_s_setprio(1);
#pragma unroll
    for (int c = 0; c < 4; ++c)
#pragma unroll
      for (int nt = 0; nt < 4; ++nt) {
        int off = (nt * 16 + col16) * 128 + (((c * 4 + quad) ^ xq) * 8);
        short8 kh8 = *(const short8*)&KhS[off];
        short8 kl8 = *(const short8*)&KlS[off];
#pragma unroll
        for (int t = 0; t < 2; ++t) {
          sacc[t][nt] = __builtin_amdgcn_mfma_f32_16x16x32_bf16(kh8, qfh[t][c], sacc[t][nt], 0, 0, 0);
          sacc[t][nt] = __builtin_amdgcn_mfma_f32_16x16x32_bf16(kh8, qfl[t][c], sacc[t][nt], 0, 0, 0);
          sacc[t][nt] = __builtin_amdgcn_mfma_f32_16x16x32_bf16(kl8, qfh[t][c], sacc[t][nt], 0, 0, 0);
        }
      }
    __builtin_amdgcn_s_setprio(0);

    // ---- B2: K-buf free on all waves; V_it (and mask) drained
    __asm__ volatile("s_waitcnt vmcnt(0)" ::: "memory");
    __builtin_amdgcn_s_barrier();

    if (it + 1 < S_LEN / 64) {   // prefetch K_{it+1}, flies under softmax+PV
#pragma unroll
      for (int j = 0; j < 4; ++j) glds16(QKh + offK[j], myK + j * 512);
#pragma unroll
      for (int j = 0; j < 4; ++j) glds16(QKl + offK[j], myKl + j * 512);
#pragma unroll
      for (int j = 0; j < 4; ++j) offK[j] += (size_t)64 * NFUSE;
    }

    // ---- online softmax (base-2), per tile; lane owns Q-row col16
#pragma unroll
    for (int t = 0; t < 2; ++t) {
      float vv[4][4];
#pragma unroll
      for (int nt = 0; nt < 4; ++nt) {
        vv[nt][0] = fmaf(mreg[t][nt].x, LOG2E, sacc[t][nt][0]);
        vv[nt][1] = fmaf(mreg[t][nt].y, LOG2E, sacc[t][nt][1]);
        vv[nt][2] = fmaf(mreg[t][nt].z, LOG2E, sacc[t][nt][2]);
        vv[nt][3] = fmaf(mreg[t][nt].w, LOG2E, sacc[t][nt][3]);
      }
      float mx = vv[0][0];
#pragma unroll
      for (int nt = 0; nt < 4; ++nt)
#pragma unroll
        for (int r = 0; r < 4; ++r) mx = fmaxf(mx, vv[nt][r]);
      mx = fmaxf(mx, __shfl_xor(mx, 16));
      mx = fmaxf(mx, __shfl_xor(mx, 32));
      float nm = fmaxf(mrow[t], mx);

      float ps = 0.f;
      u32 pk0[4], pk1[4];
#pragma unroll
      for (int nt = 0; nt < 4; ++nt) {
        union { float f; u32 u; } p0, p1, p2, p3, q0, q1, q2, q3;
        p0.f = fexp2(vv[nt][0] - nm);
        p1.f = fexp2(vv[nt][1] - nm);
        p2.f = fexp2(vv[nt][2] - nm);
        p3.f = fexp2(vv[nt][3] - nm);
        // truncate to bf16; sum the truncated values so num/denom cancel
        q0.u = p0.u & 0xffff0000u; q1.u = p1.u & 0xffff0000u;
        q2.u = p2.u & 0xffff0000u; q3.u = p3.u & 0xffff0000u;
        ps += (q0.f + q1.f) + (q2.f + q3.f);
        pk0[nt] = (p0.u >> 16) | (p1.u & 0xffff0000u);
        pk1[nt] = (p2.u >> 16) | (p3.u & 0xffff0000u);
      }
      ps += __shfl_xor(ps, 16);
      ps += __shfl_xor(ps, 32);
      float al = fexp2(mrow[t] - nm);
      lrow[t] = lrow[t] * al + ps;
      mrow[t] = nm;

      // P store: 4x b64, granule-XOR swizzled, conflict-free
      int pbase = ((t * 4 + w) * 16 + col16) * 64 + (quad & 1) * 4;
#pragma unroll
      for (int nt = 0; nt < 4; ++nt) {
        uint2 pv2; pv2.x = pk0[nt]; pv2.y = pk1[nt];
        *(uint2*)&PsS[pbase + (((2 * nt + (quad >> 1)) ^ xq) * 8)] = pv2;
      }
      // O rescale: per-lane (all rows of oacc[t] share q = col16)
#pragma unroll
      for (int d = 0; d < 8; ++d) {
        oacc[t][d][0] *= al; oacc[t][d][1] *= al;
        oacc[t][d][2] *= al; oacc[t][d][3] *= al;
      }
    }

    // ---- PV swapped: oacc[t][d] += mfma(V^T-frag, P^T-frag)
    __asm__ volatile("s_waitcnt lgkmcnt(0)" ::: "memory");  // P visible in-wave
    short8 pa[2][2];
#pragma unroll
    for (int t = 0; t < 2; ++t) {
      int pb = ((t * 4 + w) * 16 + col16) * 64;
      pa[t][0] = *(const short8*)&PsS[pb + ((quad ^ xq) * 8)];
      pa[t][1] = *(const short8*)&PsS[pb + (((4 + quad) ^ xq) * 8)];
    }
    __builtin_amdgcn_s_setprio(1);
#pragma unroll
    for (int d = 0; d < 8; ++d) {
      int vo = (d * 16 + col16) * 64;
      short8 vb0 = *(const short8*)&VtS[vo + ((quad ^ xq) * 8)];
      short8 vb1 = *(const short8*)&VtS[vo + (((4 + quad) ^ xq) * 8)];
#pragma unroll
      for (int t = 0; t < 2; ++t) {
        oacc[t][d] = __builtin_amdgcn_mfma_f32_16x16x32_bf16(vb0, pa[t][0], oacc[t][d], 0, 0, 0);
        oacc[t][d] = __builtin_amdgcn_mfma_f32_16x16x32_bf16(vb1, pa[t][1], oacc[t][d], 0, 0, 0);
      }
    }
    __builtin_amdgcn_s_setprio(0);

    // ---- B3: V-buf free on all waves; prefetch V_{it+1} (flies under next QK)
    __builtin_amdgcn_s_barrier();
    if (it + 1 < S_LEN / 64) {
#pragma unroll
      for (int j = 0; j < 4; ++j) glds16(VT + offV[j], myV + j * 512);
#pragma unroll
      for (int j = 0; j < 4; ++j) offV[j] += 64;
    }
#pragma unroll
    for (int t = 0; t < 2; ++t) pM[t] += 64;
  }

  // ---- epilogue: normalize, packed b64 stores, AO bf16 [4096][2048]
#pragma unroll
  for (int t = 0; t < 2; ++t) {
    float inv = 1.0f / lrow[t];
    int q = t0 + 64 * t + 16 * w + col16;
    short* dst = AO + (size_t)(b * S_LEN + q) * EMB + h * HDIM + quad * 4;
#pragma unroll
    for (int d = 0; d < 8; ++d) {
      short4v o4;
#pragma unroll
      for (int r = 0; r < 4; ++r) o4[r] = f2bf(oacc[t][d][r] * inv);
      *(short4v*)(dst + d * 16) = o4;
    }
  }
}

// ---------------------------------------------------------------------------
extern "C" void kernel_launch(void* const* d_in, const int* in_sizes, int n_in,
                              void* d_out, int out_size, void* d_ws, size_t ws_size,
                              hipStream_t stream) {
  const float* x    = (const float*)d_in[0];
  const float* mask = (const float*)d_in[1];
  const float* W1   = (const float*)d_in[2];
  const float* W2   = (const float*)d_in[3];
  const float* W3   = (const float*)d_in[4];
  float* out = (float*)d_out;

  char* ws = (char*)d_ws;
  size_t off = 0;
  short* xh   = (short*)(ws + off); off += (size_t)4096 * 2048 * 2;   // 16 MiB
  short* xl   = (short*)(ws + off); off += (size_t)4096 * 2048 * 2;   // 16 MiB
  short* Wth  = (short*)(ws + off); off += (size_t)NFUSE * 2048 * 2;  //  9 MiB
  short* Wtl  = (short*)(ws + off); off += (size_t)NFUSE * 2048 * 2;  //  9 MiB
  short* QKh  = (short*)(ws + off); off += (size_t)4096 * NFUSE * 2;  // 18 MiB
  short* QKl  = (short*)(ws + off); off += (size_t)4096 * NFUSE * 2;  // 18 MiB
  short* VT   = (short*)(ws + off); off += (size_t)2 * 128 * 2048 * 2;//  1 MiB
  short* AObf = (short*)(ws + off); off += (size_t)4096 * 2048 * 2;   // 16 MiB
  float* Wkv  = (float*)(ws + off); off += (size_t)2048 * 256 * 4;    //  2 MiB
  short* W3t  = xh;  // alias: xh dead after fused GEMM; W3 transpose runs after

  // 1) prep: Wkv reduce, x split, fused W^T split (W2 rows 0..2047, Wkv rows 2048..2303)
  reduce_w1_kernel<<<2048, 256, 0, stream>>>(W1, Wkv);
  split_f32_kernel<<<8192, 256, 0, stream>>>(x, xh, xl);
  transpose_split_kernel<true><<<dim3(32, 32), 256, 0, stream>>>(W2, Wth, Wtl, 2048, 2048);
  transpose_split_kernel<true><<<dim3(4, 32), 256, 0, stream>>>(
      Wkv, Wth + (size_t)2048 * 2048, Wtl + (size_t)2048 * 2048, 2048, 256);

  // 2) fused projection GEMM: [4096][2304] = x @ [W2 | Wk | Wv], split output,
  //    Q cols pre-scaled by log2e; double-buffered LDS (2x32 KiB)
  gemm_mfma<true><<<dim3(NFUSE / 128, 32), 256, 65536, stream>>>(
      xh, xl, Wth, Wtl, nullptr, QKh, QKl, 4096, NFUSE, 2048, 2048);

  // 3) V^T extraction
  build_vt<<<64, 256, 0, stream>>>(QKh, VT);

  // 4) attention
  flash_mfma<<<dim3(S_LEN / 128, 2 * NHEAD), 256, 0, stream>>>(
      QKh, QKl, VT, mask, AObf);

  // 5) output projection (plain bf16, double-buffered LDS 2x16 KiB)
  transpose_split_kernel<false><<<dim3(32, 32), 256, 0, stream>>>(W3, W3t, nullptr, 2048, 2048);
  gemm_mfma<false><<<dim3(16, 32), 256, 32768, stream>>>(
      AObf, nullptr, W3t, nullptr, out, nullptr, nullptr, 4096, 2048, 2048, 0);
}

// Round 3
// 473.031 us; speedup vs baseline: 1.2132x; 1.0461x over previous
//
#include <hip/hip_runtime.h>
#include <cstdint>

#define S_LEN 2048
#define EMB   2048
#define NHEAD 16
#define HDIM  128
#define NFUSE 2304   // fused proj width: 2048 q | 128 k | 128 v
#define LOG2E 1.4426950408889634f

typedef __attribute__((ext_vector_type(8))) _Float16 h8;
typedef __attribute__((ext_vector_type(4))) _Float16 h4;
typedef __attribute__((ext_vector_type(8))) short short8;
typedef __attribute__((ext_vector_type(4))) short short4v;
typedef __attribute__((ext_vector_type(4))) float f32x4;
typedef unsigned int u32;

// round-to-nearest-even float -> bf16 (finite inputs); used for the mask
__device__ inline short f2bf(float x) {
  union { float f; uint32_t u; } v; v.f = x;
  uint32_t r = v.u + 0x7fffu + ((v.u >> 16) & 1u);
  return (short)(r >> 16);
}
__device__ inline float bf2f(short b) {
  union { uint32_t u; float f; } v; v.u = ((uint32_t)(uint16_t)b) << 16;
  return v.f;
}
// raw v_exp_f32 (2^x); inputs are pre-scaled to log2 domain
__device__ inline float fexp2(float x) {
  float r;
  __asm__ volatile("v_exp_f32 %0, %1" : "=v"(r) : "v"(x));
  return r;
}
// pack 2 f32 -> 2 f16 (RTZ), result as u32
__device__ inline u32 pkrtz(float a, float b) {
  u32 r;
  __asm__ volatile("v_cvt_pkrtz_f16_f32 %0, %1, %2" : "=v"(r) : "v"(a), "v"(b));
  return r;
}
// async global->LDS, 16B per lane; lds base must be wave-uniform
__device__ inline void glds16(const void* g, void* l) {
  __builtin_amdgcn_global_load_lds(
      (const __attribute__((address_space(1))) u32*)g,
      (__attribute__((address_space(3))) u32*)l, 16, 0, 0);
}

// ---------------------------------------------------------------------------
// W1 group-reduce -> Wkv f32 [2048][256] (k cols 0..127, v cols 128..255)
// ---------------------------------------------------------------------------
__global__ __launch_bounds__(256) void reduce_w1_kernel(
    const float* __restrict__ W1, float* __restrict__ Wkv) {
  int idx = blockIdx.x * 256 + threadIdx.x;
  int i = idx >> 8;
  int c = idx & 255;
  int base = (c < 128) ? c : (c + 384);
  const float* r = W1 + (size_t)i * 1024 + base;
  Wkv[idx] = (r[0] + r[128]) + (r[256] + r[384]);
}

// ---------------------------------------------------------------------------
// elementwise f32 -> fp16; 4 elements/thread
// ---------------------------------------------------------------------------
__global__ __launch_bounds__(256) void cvt_x_kernel(
    const float* __restrict__ src, _Float16* __restrict__ dst) {
  size_t idx = (size_t)blockIdx.x * 256 + threadIdx.x;
  float4 v = *(const float4*)(src + idx * 4);
  h4 o;
  o[0] = (_Float16)v.x; o[1] = (_Float16)v.y;
  o[2] = (_Float16)v.z; o[3] = (_Float16)v.w;
  *(h4*)(dst + idx * 4) = o;
}

// ---------------------------------------------------------------------------
// mask f32 -> bf16 scaled by log2e (flash adds it to log2-domain logits)
// ---------------------------------------------------------------------------
__global__ __launch_bounds__(256) void cvt_mask_kernel(
    const float* __restrict__ src, short* __restrict__ dst) {
  size_t idx = (size_t)blockIdx.x * 256 + threadIdx.x;
  float4 v = *(const float4*)(src + idx * 4);
  short4v o;
  o[0] = f2bf(v.x * LOG2E); o[1] = f2bf(v.y * LOG2E);
  o[2] = f2bf(v.z * LOG2E); o[3] = f2bf(v.w * LOG2E);
  *(short4v*)(dst + idx * 4) = o;
}

// ---------------------------------------------------------------------------
// tiled transpose f32 W[K][N] -> fp16 T[N][K]; grid (N/64, K/64), 256 thr
// ---------------------------------------------------------------------------
__global__ __launch_bounds__(256) void transpose_f16_kernel(
    const float* __restrict__ W, _Float16* __restrict__ T, int K, int N) {
  __shared__ float Tt[64][65];
  const int tid = threadIdx.x;
  const int k0 = blockIdx.y * 64, n0 = blockIdx.x * 64;
  {
    int r = tid >> 2, c0 = (tid & 3) * 16;
    const float* src = W + (size_t)(k0 + r) * N + n0 + c0;
#pragma unroll
    for (int j = 0; j < 4; ++j) {
      float4 v = *(const float4*)(src + 4 * j);
      Tt[r][c0 + 4 * j + 0] = v.x; Tt[r][c0 + 4 * j + 1] = v.y;
      Tt[r][c0 + 4 * j + 2] = v.z; Tt[r][c0 + 4 * j + 3] = v.w;
    }
  }
  __syncthreads();
  {
    int n = tid >> 2, kc = (tid & 3) * 16;
    h8 o0, o1;
#pragma unroll
    for (int i = 0; i < 8; ++i) {
      o0[i] = (_Float16)Tt[kc + i][n];
      o1[i] = (_Float16)Tt[kc + 8 + i][n];
    }
    size_t off = (size_t)(n0 + n) * K + k0 + kc;
    *(h8*)(T + off) = o0;
    *(h8*)(T + off + 8) = o1;
  }
}

// ---------------------------------------------------------------------------
// fp16 MFMA GEMM: C[M][N] = A[M][K] @ B (Bt = B^T as [N][K] fp16).
// QSCALE: fp16 C out, cols < qlim scaled by log2e. else: f32 C out.
// 128x128 tile, BK=32, 4 waves; double-buffered LDS (2x16 KiB),
// global_load_lds staging, counted s_waitcnt vmcnt(4).
// ---------------------------------------------------------------------------
template <bool QSCALE>
__global__ __launch_bounds__(256, 3) void gemm_f16(
    const _Float16* __restrict__ A, const _Float16* __restrict__ Bt,
    float* __restrict__ C, _Float16* __restrict__ Cf,
    int M, int N, int K, int qlim) {
  extern __shared__ char smraw[];
  _Float16* sm = (_Float16*)smraw;
  const int BUFS = 8192;  // elements per buffer (A 4096 | B 4096)

  const int tid  = threadIdx.x;
  const int w    = tid >> 6;
  const int lane = tid & 63;
  const int quad = lane >> 4, col16 = lane & 15;
  const int row0 = blockIdx.y * 128, col0 = blockIdx.x * 128;
  const float esc = (col0 < qlim) ? LOG2E : 1.0f;

  const int srow  = w * 32 + (lane >> 2);
  const int kpart = (lane & 3) * 8;
  const _Float16* pA0 = A + (size_t)(row0 + srow) * K + kpart;
  const _Float16* pA1 = pA0 + (size_t)16 * K;
  const _Float16* pB0 = Bt + (size_t)(col0 + srow) * K + kpart;
  const _Float16* pB1 = pB0 + (size_t)16 * K;

  const int oA0 = (w * 32) * 32, oA1 = (w * 32 + 16) * 32;
  const int oB0 = 4096 + (w * 32) * 32, oB1 = 4096 + (w * 32 + 16) * 32;

#define STAGE_GEMM(bo)                                                        \
  do {                                                                        \
    glds16(pA0, sm + (bo) + oA0); glds16(pA1, sm + (bo) + oA1);               \
    glds16(pB0, sm + (bo) + oB0); glds16(pB1, sm + (bo) + oB1);               \
    pA0 += 32; pA1 += 32; pB0 += 32; pB1 += 32;                               \
  } while (0)

  f32x4 acc[2][8];
#pragma unroll
  for (int mt = 0; mt < 2; ++mt)
#pragma unroll
    for (int nt = 0; nt < 8; ++nt) {
      acc[mt][nt][0] = 0.f; acc[mt][nt][1] = 0.f;
      acc[mt][nt][2] = 0.f; acc[mt][nt][3] = 0.f;
    }

  const int nchunk = K >> 5;
  int bo = 0;
  STAGE_GEMM(0);

#pragma unroll 1
  for (int c = 0; c < nchunk; ++c) {
    if (c + 1 < nchunk) {
      STAGE_GEMM(bo ^ BUFS);
      __asm__ volatile("s_waitcnt vmcnt(4)" ::: "memory");
    } else {
      __asm__ volatile("s_waitcnt vmcnt(0)" ::: "memory");
    }
    __builtin_amdgcn_s_barrier();

    const _Float16* AS = sm + bo;
    const _Float16* BS = sm + bo + 4096;

    h8 af[2];
#pragma unroll
    for (int mt = 0; mt < 2; ++mt)
      af[mt] = *(const h8*)&AS[(w * 32 + mt * 16 + col16) * 32 + quad * 8];
#pragma unroll
    for (int nt = 0; nt < 8; ++nt) {
      h8 b8 = *(const h8*)&BS[(nt * 16 + col16) * 32 + quad * 8];
#pragma unroll
      for (int mt = 0; mt < 2; ++mt)
        acc[mt][nt] = __builtin_amdgcn_mfma_f32_16x16x32_f16(af[mt], b8, acc[mt][nt], 0, 0, 0);
    }
    __builtin_amdgcn_s_barrier();
    bo ^= BUFS;
  }
#undef STAGE_GEMM

#pragma unroll
  for (int mt = 0; mt < 2; ++mt)
#pragma unroll
    for (int nt = 0; nt < 8; ++nt)
#pragma unroll
      for (int r = 0; r < 4; ++r) {
        int row = row0 + w * 32 + mt * 16 + quad * 4 + r;
        int col = col0 + nt * 16 + col16;
        float v = acc[mt][nt][r];
        if constexpr (QSCALE) {
          Cf[(size_t)row * N + col] = (_Float16)(v * esc);
        } else {
          C[(size_t)row * N + col] = v;
        }
      }
}

// ---------------------------------------------------------------------------
// build VT fp16 [2][128][2048] from fused proj output cols 2176..2303 (v)
// grid 64 blocks x 256 thr; block = 64 s-rows  (bit-preserving short copies)
// ---------------------------------------------------------------------------
__global__ __launch_bounds__(256) void build_vt(
    const short* __restrict__ QKh, short* __restrict__ VT) {
  __shared__ short T[64][136];
  const int tid = threadIdx.x;
  const int gs = blockIdx.x * 64;
  const int b = gs >> 11;
  const int s = gs & 2047;
  {
    int r = tid >> 2, c0 = (tid & 3) * 32;
    const short* src = QKh + (size_t)(gs + r) * NFUSE + 2176 + c0;
#pragma unroll
    for (int j = 0; j < 4; ++j)
      *(short8*)&T[r][c0 + 8 * j] = *(const short8*)(src + 8 * j);
  }
  __syncthreads();
  {
    int d = tid >> 1, c = (tid & 1) * 32;
    short* dst = VT + (size_t)(b * HDIM + d) * S_LEN + s + c;
#pragma unroll
    for (int jo = 0; jo < 4; ++jo) {
      short8 o;
#pragma unroll
      for (int i = 0; i < 8; ++i) o[i] = T[c + jo * 8 + i][d];
      *(short8*)(dst + jo * 8) = o;
    }
  }
}

// ---------------------------------------------------------------------------
// fp16 MFMA flash attention, BM=128 (2 Q-tiles/wave), BN=64, swapped operands.
//  * single-pass fp16 QK^T (was 3-pass split-bf16): 32+32 MFMAs/iter/wave.
//  * mask pre-converted to bf16*log2e (halves mask traffic, drops the fmaf).
//  * LDS 48 KiB (K 16 | V 16 | P 16) -> 3 blocks/CU.
//  * defer-max (T13, THR=8 in log2 domain): skip O-rescale when the wave's
//    tile max doesn't beat the running max by >8.
//  * pipeline as before: K_{i+1} after QK, V_{i+1} after PV, vmcnt(4) at B1.
// grid (S/128, B*H), 256 threads = 4 waves.
// ---------------------------------------------------------------------------
__global__ __launch_bounds__(256, 3) void flash_f16(
    const _Float16* __restrict__ QKf, const _Float16* __restrict__ VT,
    const short* __restrict__ maskb, _Float16* __restrict__ AO) {
  __shared__ _Float16 KS[64 * 128];        // 16 KiB, [64 s][128 d] swizzled
  __shared__ _Float16 VtS[128 * 64];       // 16 KiB, [128 d][64 s] swizzled
  __shared__ _Float16 PsS[2 * 4 * 16 * 64];// 16 KiB, [tile][wave][16 q][64 s]

  const int tid   = threadIdx.x;
  const int w     = tid >> 6;
  const int lane  = tid & 63;
  const int quad  = lane >> 4;
  const int col16 = lane & 15;
  const int xq    = col16 & 7;
  const int bh = blockIdx.y, b = bh >> 4, h = bh & 15;
  const int t0 = blockIdx.x * 128;

  const int jr = lane >> 4;   // K/Q staging: row-within-instr 0..3
  const int kg = lane & 15;   // K/Q staging: dest granule (16B units)
  const int vr = lane >> 3;   // V staging: row-within-instr 0..7
  const int vg = lane & 7;    // V staging: dest granule

  _Float16* myK = KS + w * 2048;   // wave staging region: 16 rows x 128
  _Float16* myV = VtS + w * 2048;  // wave staging region: 32 d-rows x 64

  // ---- Q prologue: wave-local glds staging + fragment extraction
  h8 qf[2][4];
#pragma unroll
  for (int t = 0; t < 2; ++t) {
#pragma unroll
    for (int j = 0; j < 4; ++j) {
      int rl = 4 * j + jr;
      int gq = kg ^ (rl & 7);
      size_t go = (size_t)(b * S_LEN + t0 + 64 * t + 16 * w + rl) * NFUSE
                + h * HDIM + gq * 8;
      glds16(QKf + go, myK + j * 512);
    }
    __asm__ volatile("s_waitcnt vmcnt(0)" ::: "memory");
#pragma unroll
    for (int c = 0; c < 4; ++c)
      qf[t][c] = *(const h8*)&myK[col16 * 128 + (((c * 4 + quad) ^ xq) * 8)];
    __asm__ volatile("s_waitcnt lgkmcnt(0)" ::: "memory");  // reads retired
  }

  // ---- per-lane staging offsets (source swizzled; LDS linear)
  size_t offK[4], offV[4];
#pragma unroll
  for (int j = 0; j < 4; ++j) {
    int rl = 4 * j + jr;
    offK[j] = (size_t)(b * S_LEN + 16 * w + rl) * NFUSE + 2048
            + (size_t)((kg ^ (rl & 7)) * 8);
    int dl = 32 * w + 8 * j + vr;
    offV[j] = (size_t)(b * HDIM + dl) * S_LEN + (size_t)((vg ^ (vr & 7)) * 8);
  }
  const short* pM[2];
#pragma unroll
  for (int t = 0; t < 2; ++t)
    pM[t] = maskb + (size_t)b * S_LEN * S_LEN
          + (size_t)(t0 + 64 * t + 16 * w + col16) * S_LEN + quad * 4;

  // ---- issue K_0 then V_0 (queue discipline: [K4, V4])
#pragma unroll
  for (int j = 0; j < 4; ++j) glds16(QKf + offK[j], myK + j * 512);
#pragma unroll
  for (int j = 0; j < 4; ++j) glds16(VT + offV[j], myV + j * 512);
#pragma unroll
  for (int j = 0; j < 4; ++j) { offK[j] += (size_t)64 * NFUSE; offV[j] += 64; }

  f32x4 oacc[2][8];
#pragma unroll
  for (int t = 0; t < 2; ++t)
#pragma unroll
    for (int d = 0; d < 8; ++d) {
      oacc[t][d][0] = 0.f; oacc[t][d][1] = 0.f;
      oacc[t][d][2] = 0.f; oacc[t][d][3] = 0.f;
    }
  float mrow[2] = {-3.0e38f, -3.0e38f};
  float lrow[2] = {0.f, 0.f};

#pragma unroll 1
  for (int it = 0; it < S_LEN / 64; ++it) {
    // ---- B1: K_it arrived on all waves (V_it still in flight)
    __asm__ volatile("s_waitcnt vmcnt(4)" ::: "memory");
    __builtin_amdgcn_s_barrier();

    // mask for this tile (bf16x4 per nt), flies under QK MFMAs
    short4v msk[2][4];
#pragma unroll
    for (int t = 0; t < 2; ++t)
#pragma unroll
      for (int nt = 0; nt < 4; ++nt)
        msk[t][nt] = *(const short4v*)(pM[t] + nt * 16);

    // ---- QK^T swapped: sacc[t][nt] = S^T (rows = s-local, cols = q)
    f32x4 sacc[2][4];
#pragma unroll
    for (int t = 0; t < 2; ++t)
#pragma unroll
      for (int nt = 0; nt < 4; ++nt) {
        sacc[t][nt][0] = 0.f; sacc[t][nt][1] = 0.f;
        sacc[t][nt][2] = 0.f; sacc[t][nt][3] = 0.f;
      }
    __builtin_amdgcn_s_setprio(1);
#pragma unroll
    for (int c = 0; c < 4; ++c)
#pragma unroll
      for (int nt = 0; nt < 4; ++nt) {
        h8 k8 = *(const h8*)&KS[(nt * 16 + col16) * 128 + (((c * 4 + quad) ^ xq) * 8)];
#pragma unroll
        for (int t = 0; t < 2; ++t)
          sacc[t][nt] = __builtin_amdgcn_mfma_f32_16x16x32_f16(k8, qf[t][c], sacc[t][nt], 0, 0, 0);
      }
    __builtin_amdgcn_s_setprio(0);

    // ---- B2: K-buf free on all waves; V_it (and mask) drained
    __asm__ volatile("s_waitcnt vmcnt(0)" ::: "memory");
    __builtin_amdgcn_s_barrier();

    if (it + 1 < S_LEN / 64) {   // prefetch K_{it+1}, flies under softmax+PV
#pragma unroll
      for (int j = 0; j < 4; ++j) glds16(QKf + offK[j], myK + j * 512);
#pragma unroll
      for (int j = 0; j < 4; ++j) offK[j] += (size_t)64 * NFUSE;
    }

    // ---- online softmax (base-2), per tile; lane owns Q-row col16
#pragma unroll
    for (int t = 0; t < 2; ++t) {
      float vv[4][4];
#pragma unroll
      for (int nt = 0; nt < 4; ++nt)
#pragma unroll
        for (int r = 0; r < 4; ++r)
          vv[nt][r] = sacc[t][nt][r] + bf2f(msk[t][nt][r]);
      float mx = vv[0][0];
#pragma unroll
      for (int nt = 0; nt < 4; ++nt)
#pragma unroll
        for (int r = 0; r < 4; ++r) mx = fmaxf(mx, vv[nt][r]);
      mx = fmaxf(mx, __shfl_xor(mx, 16));
      mx = fmaxf(mx, __shfl_xor(mx, 32));

      float nm = fmaxf(mrow[t], mx);
      if (__all(mx - mrow[t] <= 8.0f)) {
        nm = mrow[t];                       // defer: P bounded by 2^8
      } else {
        float al = fexp2(mrow[t] - nm);
        lrow[t] *= al;
#pragma unroll
        for (int d = 0; d < 8; ++d) {
          oacc[t][d][0] *= al; oacc[t][d][1] *= al;
          oacc[t][d][2] *= al; oacc[t][d][3] *= al;
        }
        mrow[t] = nm;
      }

      float ps = 0.f;
      u32 pk0[4], pk1[4];
#pragma unroll
      for (int nt = 0; nt < 4; ++nt) {
        float p0 = fexp2(vv[nt][0] - nm);
        float p1 = fexp2(vv[nt][1] - nm);
        float p2 = fexp2(vv[nt][2] - nm);
        float p3 = fexp2(vv[nt][3] - nm);
        ps += (p0 + p1) + (p2 + p3);
        pk0[nt] = pkrtz(p0, p1);
        pk1[nt] = pkrtz(p2, p3);
      }
      ps += __shfl_xor(ps, 16);
      ps += __shfl_xor(ps, 32);
      lrow[t] += ps;

      // P store: 4x b64, granule-XOR swizzled
      int pbase = ((t * 4 + w) * 16 + col16) * 64 + (quad & 1) * 4;
#pragma unroll
      for (int nt = 0; nt < 4; ++nt) {
        uint2 pv2; pv2.x = pk0[nt]; pv2.y = pk1[nt];
        *(uint2*)&PsS[pbase + (((2 * nt + (quad >> 1)) ^ xq) * 8)] = pv2;
      }
    }

    // ---- PV swapped: oacc[t][d] += mfma(V^T-frag, P^T-frag)
    __asm__ volatile("s_waitcnt lgkmcnt(0)" ::: "memory");  // P visible in-wave
    h8 pa[2][2];
#pragma unroll
    for (int t = 0; t < 2; ++t) {
      int pb = ((t * 4 + w) * 16 + col16) * 64;
      pa[t][0] = *(const h8*)&PsS[pb + ((quad ^ xq) * 8)];
      pa[t][1] = *(const h8*)&PsS[pb + (((4 + quad) ^ xq) * 8)];
    }
    __builtin_amdgcn_s_setprio(1);
#pragma unroll
    for (int d = 0; d < 8; ++d) {
      int vo = (d * 16 + col16) * 64;
      h8 vb0 = *(const h8*)&VtS[vo + ((quad ^ xq) * 8)];
      h8 vb1 = *(const h8*)&VtS[vo + (((4 + quad) ^ xq) * 8)];
#pragma unroll
      for (int t = 0; t < 2; ++t) {
        oacc[t][d] = __builtin_amdgcn_mfma_f32_16x16x32_f16(vb0, pa[t][0], oacc[t][d], 0, 0, 0);
        oacc[t][d] = __builtin_amdgcn_mfma_f32_16x16x32_f16(vb1, pa[t][1], oacc[t][d], 0, 0, 0);
      }
    }
    __builtin_amdgcn_s_setprio(0);

    // ---- B3: V-buf free on all waves; prefetch V_{it+1}
    __builtin_amdgcn_s_barrier();
    if (it + 1 < S_LEN / 64) {
#pragma unroll
      for (int j = 0; j < 4; ++j) glds16(VT + offV[j], myV + j * 512);
#pragma unroll
      for (int j = 0; j < 4; ++j) offV[j] += 64;
    }
#pragma unroll
    for (int t = 0; t < 2; ++t) pM[t] += 64;
  }

  // ---- epilogue: normalize, packed 8B stores, AO fp16 [4096][2048]
#pragma unroll
  for (int t = 0; t < 2; ++t) {
    float inv = 1.0f / lrow[t];
    int q = t0 + 64 * t + 16 * w + col16;
    _Float16* dst = AO + (size_t)(b * S_LEN + q) * EMB + h * HDIM + quad * 4;
#pragma unroll
    for (int d = 0; d < 8; ++d) {
      h4 o4;
#pragma unroll
      for (int r = 0; r < 4; ++r) o4[r] = (_Float16)(oacc[t][d][r] * inv);
      *(h4*)(dst + d * 16) = o4;
    }
  }
}

// ---------------------------------------------------------------------------
extern "C" void kernel_launch(void* const* d_in, const int* in_sizes, int n_in,
                              void* d_out, int out_size, void* d_ws, size_t ws_size,
                              hipStream_t stream) {
  const float* x    = (const float*)d_in[0];
  const float* mask = (const float*)d_in[1];
  const float* W1   = (const float*)d_in[2];
  const float* W2   = (const float*)d_in[3];
  const float* W3   = (const float*)d_in[4];
  float* out = (float*)d_out;

  char* ws = (char*)d_ws;
  size_t off = 0;
  _Float16* xf   = (_Float16*)(ws + off); off += (size_t)4096 * 2048 * 2;    // 16 MiB
  _Float16* Wtf  = (_Float16*)(ws + off); off += (size_t)NFUSE * 2048 * 2;   //  9 MiB
  _Float16* QKf  = (_Float16*)(ws + off); off += (size_t)4096 * NFUSE * 2;   // 18 MiB
  _Float16* VT   = (_Float16*)(ws + off); off += (size_t)2 * 128 * 2048 * 2; //  1 MiB
  _Float16* AOf  = (_Float16*)(ws + off); off += (size_t)4096 * 2048 * 2;    // 16 MiB
  float*    Wkv  = (float*)(ws + off);    off += (size_t)2048 * 256 * 4;     //  2 MiB
  short*    maskb= (short*)(ws + off);    off += (size_t)2 * 2048 * 2048 * 2;// 16 MiB
  _Float16* W3t  = xf;  // alias: xf dead after fused GEMM; W3 transpose runs after

  // 1) prep: Wkv reduce, x->fp16, mask->bf16*log2e, fused W^T fp16
  reduce_w1_kernel<<<2048, 256, 0, stream>>>(W1, Wkv);
  cvt_x_kernel<<<8192, 256, 0, stream>>>(x, xf);
  cvt_mask_kernel<<<8192, 256, 0, stream>>>(mask, maskb);
  transpose_f16_kernel<<<dim3(32, 32), 256, 0, stream>>>(W2, Wtf, 2048, 2048);
  transpose_f16_kernel<<<dim3(4, 32), 256, 0, stream>>>(
      Wkv, Wtf + (size_t)2048 * 2048, 2048, 256);

  // 2) fused projection GEMM: [4096][2304] = x @ [W2 | Wk | Wv], fp16 out,
  //    Q cols pre-scaled by log2e
  gemm_f16<true><<<dim3(NFUSE / 128, 32), 256, 32768, stream>>>(
      xf, Wtf, nullptr, QKf, 4096, NFUSE, 2048, 2048);

  // 3) V^T extraction
  build_vt<<<64, 256, 0, stream>>>((const short*)QKf, (short*)VT);

  // 4) attention
  flash_f16<<<dim3(S_LEN / 128, 2 * NHEAD), 256, 0, stream>>>(
      QKf, VT, maskb, AOf);

  // 5) output projection (fp16 in, f32 out)
  transpose_f16_kernel<<<dim3(32, 32), 256, 0, stream>>>(W3, W3t, 2048, 2048);
  gemm_f16<false><<<dim3(16, 32), 256, 32768, stream>>>(
      AOf, W3t, out, nullptr, 4096, 2048, 2048, 0);
}

// Round 4
// 365.677 us; speedup vs baseline: 1.5693x; 1.2936x over previous
//
#include <hip/hip_runtime.h>
#include <cstdint>

#define S_LEN 2048
#define EMB   2048
#define NHEAD 16
#define HDIM  128
#define NFUSE 2304   // fused proj width: 2048 q | 128 k | 128 v
#define LOG2E 1.4426950408889634f

typedef __attribute__((ext_vector_type(8))) _Float16 h8;
typedef __attribute__((ext_vector_type(4))) _Float16 h4;
typedef __attribute__((ext_vector_type(8))) short short8;
typedef __attribute__((ext_vector_type(4))) short short4v;
typedef __attribute__((ext_vector_type(4))) float f32x4;
typedef unsigned int u32;

// round-to-nearest-even float -> bf16 (finite inputs); used for the mask
__device__ inline short f2bf(float x) {
  union { float f; uint32_t u; } v; v.f = x;
  uint32_t r = v.u + 0x7fffu + ((v.u >> 16) & 1u);
  return (short)(r >> 16);
}
__device__ inline float bf2f(short b) {
  union { uint32_t u; float f; } v; v.u = ((uint32_t)(uint16_t)b) << 16;
  return v.f;
}
// raw v_exp_f32 (2^x); inputs are pre-scaled to log2 domain
__device__ inline float fexp2(float x) {
  float r;
  __asm__ volatile("v_exp_f32 %0, %1" : "=v"(r) : "v"(x));
  return r;
}
// pack 2 f32 -> 2 f16 (RTZ), result as u32
__device__ inline u32 pkrtz(float a, float b) {
  u32 r;
  __asm__ volatile("v_cvt_pkrtz_f16_f32 %0, %1, %2" : "=v"(r) : "v"(a), "v"(b));
  return r;
}
// async global->LDS, 16B per lane; lds base must be wave-uniform
__device__ inline void glds16(const void* g, void* l) {
  __builtin_amdgcn_global_load_lds(
      (const __attribute__((address_space(1))) u32*)g,
      (__attribute__((address_space(3))) u32*)l, 16, 0, 0);
}

// ---------------------------------------------------------------------------
// W1 group-reduce -> Wkv f32 [2048][256] (k cols 0..127, v cols 128..255)
// ---------------------------------------------------------------------------
__global__ __launch_bounds__(256) void reduce_w1_kernel(
    const float* __restrict__ W1, float* __restrict__ Wkv) {
  int idx = blockIdx.x * 256 + threadIdx.x;
  int i = idx >> 8;
  int c = idx & 255;
  int base = (c < 128) ? c : (c + 384);
  const float* r = W1 + (size_t)i * 1024 + base;
  Wkv[idx] = (r[0] + r[128]) + (r[256] + r[384]);
}

// ---------------------------------------------------------------------------
// elementwise f32 -> fp16; 4 elements/thread
// ---------------------------------------------------------------------------
__global__ __launch_bounds__(256) void cvt_x_kernel(
    const float* __restrict__ src, _Float16* __restrict__ dst) {
  size_t idx = (size_t)blockIdx.x * 256 + threadIdx.x;
  float4 v = *(const float4*)(src + idx * 4);
  h4 o;
  o[0] = (_Float16)v.x; o[1] = (_Float16)v.y;
  o[2] = (_Float16)v.z; o[3] = (_Float16)v.w;
  *(h4*)(dst + idx * 4) = o;
}

// ---------------------------------------------------------------------------
// mask f32 -> bf16 scaled by log2e (flash adds it to log2-domain logits)
// ---------------------------------------------------------------------------
__global__ __launch_bounds__(256) void cvt_mask_kernel(
    const float* __restrict__ src, short* __restrict__ dst) {
  size_t idx = (size_t)blockIdx.x * 256 + threadIdx.x;
  float4 v = *(const float4*)(src + idx * 4);
  short4v o;
  o[0] = f2bf(v.x * LOG2E); o[1] = f2bf(v.y * LOG2E);
  o[2] = f2bf(v.z * LOG2E); o[3] = f2bf(v.w * LOG2E);
  *(short4v*)(dst + idx * 4) = o;
}

// ---------------------------------------------------------------------------
// tiled transpose f32 W[K][N] -> fp16 T[N][K]; grid (N/64, K/64), 256 thr
// ---------------------------------------------------------------------------
__global__ __launch_bounds__(256) void transpose_f16_kernel(
    const float* __restrict__ W, _Float16* __restrict__ T, int K, int N) {
  __shared__ float Tt[64][65];
  const int tid = threadIdx.x;
  const int k0 = blockIdx.y * 64, n0 = blockIdx.x * 64;
  {
    int r = tid >> 2, c0 = (tid & 3) * 16;
    const float* src = W + (size_t)(k0 + r) * N + n0 + c0;
#pragma unroll
    for (int j = 0; j < 4; ++j) {
      float4 v = *(const float4*)(src + 4 * j);
      Tt[r][c0 + 4 * j + 0] = v.x; Tt[r][c0 + 4 * j + 1] = v.y;
      Tt[r][c0 + 4 * j + 2] = v.z; Tt[r][c0 + 4 * j + 3] = v.w;
    }
  }
  __syncthreads();
  {
    int n = tid >> 2, kc = (tid & 3) * 16;
    h8 o0, o1;
#pragma unroll
    for (int i = 0; i < 8; ++i) {
      o0[i] = (_Float16)Tt[kc + i][n];
      o1[i] = (_Float16)Tt[kc + 8 + i][n];
    }
    size_t off = (size_t)(n0 + n) * K + k0 + kc;
    *(h8*)(T + off) = o0;
    *(h8*)(T + off + 8) = o1;
  }
}

// ---------------------------------------------------------------------------
// fp16 MFMA GEMM: C[M][N] = A[M][K] @ B (Bt = B^T as [N][K] fp16).
// QSCALE: fp16 C out, cols < qlim scaled by log2e. else: f32 C out.
// 128x128 tile, BK=32, 4 waves; double-buffered LDS (2x16 KiB),
// global_load_lds staging, counted s_waitcnt vmcnt(4).
// ---------------------------------------------------------------------------
template <bool QSCALE>
__global__ __launch_bounds__(256, 3) void gemm_f16(
    const _Float16* __restrict__ A, const _Float16* __restrict__ Bt,
    float* __restrict__ C, _Float16* __restrict__ Cf,
    int M, int N, int K, int qlim) {
  extern __shared__ char smraw[];
  _Float16* sm = (_Float16*)smraw;
  const int BUFS = 8192;  // elements per buffer (A 4096 | B 4096)

  const int tid  = threadIdx.x;
  const int w    = tid >> 6;
  const int lane = tid & 63;
  const int quad = lane >> 4, col16 = lane & 15;
  const int row0 = blockIdx.y * 128, col0 = blockIdx.x * 128;
  const float esc = (col0 < qlim) ? LOG2E : 1.0f;

  const int srow  = w * 32 + (lane >> 2);
  const int kpart = (lane & 3) * 8;
  const _Float16* pA0 = A + (size_t)(row0 + srow) * K + kpart;
  const _Float16* pA1 = pA0 + (size_t)16 * K;
  const _Float16* pB0 = Bt + (size_t)(col0 + srow) * K + kpart;
  const _Float16* pB1 = pB0 + (size_t)16 * K;

  const int oA0 = (w * 32) * 32, oA1 = (w * 32 + 16) * 32;
  const int oB0 = 4096 + (w * 32) * 32, oB1 = 4096 + (w * 32 + 16) * 32;

#define STAGE_GEMM(bo)                                                        \
  do {                                                                        \
    glds16(pA0, sm + (bo) + oA0); glds16(pA1, sm + (bo) + oA1);               \
    glds16(pB0, sm + (bo) + oB0); glds16(pB1, sm + (bo) + oB1);               \
    pA0 += 32; pA1 += 32; pB0 += 32; pB1 += 32;                               \
  } while (0)

  f32x4 acc[2][8];
#pragma unroll
  for (int mt = 0; mt < 2; ++mt)
#pragma unroll
    for (int nt = 0; nt < 8; ++nt) {
      acc[mt][nt][0] = 0.f; acc[mt][nt][1] = 0.f;
      acc[mt][nt][2] = 0.f; acc[mt][nt][3] = 0.f;
    }

  const int nchunk = K >> 5;
  int bo = 0;
  STAGE_GEMM(0);

#pragma unroll 1
  for (int c = 0; c < nchunk; ++c) {
    if (c + 1 < nchunk) {
      STAGE_GEMM(bo ^ BUFS);
      __asm__ volatile("s_waitcnt vmcnt(4)" ::: "memory");
    } else {
      __asm__ volatile("s_waitcnt vmcnt(0)" ::: "memory");
    }
    __builtin_amdgcn_s_barrier();

    const _Float16* AS = sm + bo;
    const _Float16* BS = sm + bo + 4096;

    h8 af[2];
#pragma unroll
    for (int mt = 0; mt < 2; ++mt)
      af[mt] = *(const h8*)&AS[(w * 32 + mt * 16 + col16) * 32 + quad * 8];
#pragma unroll
    for (int nt = 0; nt < 8; ++nt) {
      h8 b8 = *(const h8*)&BS[(nt * 16 + col16) * 32 + quad * 8];
#pragma unroll
      for (int mt = 0; mt < 2; ++mt)
        acc[mt][nt] = __builtin_amdgcn_mfma_f32_16x16x32_f16(af[mt], b8, acc[mt][nt], 0, 0, 0);
    }
    __builtin_amdgcn_s_barrier();
    bo ^= BUFS;
  }
#undef STAGE_GEMM

#pragma unroll
  for (int mt = 0; mt < 2; ++mt)
#pragma unroll
    for (int nt = 0; nt < 8; ++nt)
#pragma unroll
      for (int r = 0; r < 4; ++r) {
        int row = row0 + w * 32 + mt * 16 + quad * 4 + r;
        int col = col0 + nt * 16 + col16;
        float v = acc[mt][nt][r];
        if constexpr (QSCALE) {
          Cf[(size_t)row * N + col] = (_Float16)(v * esc);
        } else {
          C[(size_t)row * N + col] = v;
        }
      }
}

// ---------------------------------------------------------------------------
// build VT fp16 [2][128][2048] from fused proj output cols 2176..2303 (v)
// grid 64 blocks x 256 thr; block = 64 s-rows  (bit-preserving short copies)
// ---------------------------------------------------------------------------
__global__ __launch_bounds__(256) void build_vt(
    const short* __restrict__ QKh, short* __restrict__ VT) {
  __shared__ short T[64][136];
  const int tid = threadIdx.x;
  const int gs = blockIdx.x * 64;
  const int b = gs >> 11;
  const int s = gs & 2047;
  {
    int r = tid >> 2, c0 = (tid & 3) * 32;
    const short* src = QKh + (size_t)(gs + r) * NFUSE + 2176 + c0;
#pragma unroll
    for (int j = 0; j < 4; ++j)
      *(short8*)&T[r][c0 + 8 * j] = *(const short8*)(src + 8 * j);
  }
  __syncthreads();
  {
    int d = tid >> 1, c = (tid & 1) * 32;
    short* dst = VT + (size_t)(b * HDIM + d) * S_LEN + s + c;
#pragma unroll
    for (int jo = 0; jo < 4; ++jo) {
      short8 o;
#pragma unroll
      for (int i = 0; i < 8; ++i) o[i] = T[c + jo * 8 + i][d];
      *(short8*)(dst + jo * 8) = o;
    }
  }
}

// ---------------------------------------------------------------------------
// fp16 MFMA flash attention, BM=128 (2 Q-tiles/wave), BN=64, swapped operands.
//  * single-pass fp16 QK^T; mask pre-converted to bf16*log2e.
//  * mask staged per-WAVE into private LDS via 4 coalesced glds16/iter
//    (XOR-swizzled source, swizzled ds_read_b64 readback) -- no barriers.
//  * LDS 64 KiB (K 16 | V 16 | P 16 | M 16) -> 2 blocks/CU.
//  * launch_bounds (256,2): ~190 unified regs, NO scratch spill (the (256,3)
//    variant spilled: VGPR 84, 127 MB scratch writeback, +35 us).
//  * defer-max (T13, THR=8 in log2 domain).
//  * pipeline: queue/wave = [K4, M4, V4]; B1 waits vmcnt(8) (K arrived);
//    B2 vmcnt(0) (M+V arrived); K+M prefetch after B2, V prefetch after B3.
// grid (S/128, B*H), 256 threads = 4 waves.
// ---------------------------------------------------------------------------
__global__ __launch_bounds__(256, 2) void flash_f16(
    const _Float16* __restrict__ QKf, const _Float16* __restrict__ VT,
    const short* __restrict__ maskb, _Float16* __restrict__ AO) {
  __shared__ _Float16 KS[64 * 128];        // 16 KiB, [64 s][128 d] swizzled
  __shared__ _Float16 VtS[128 * 64];       // 16 KiB, [128 d][64 s] swizzled
  __shared__ _Float16 PsS[2 * 4 * 16 * 64];// 16 KiB, [tile][wave][16 q][64 s]
  __shared__ short    MkS[4 * 32 * 64];    // 16 KiB, [wave][32 q-rows][64 s]

  const int tid   = threadIdx.x;
  const int w     = tid >> 6;
  const int lane  = tid & 63;
  const int quad  = lane >> 4;
  const int col16 = lane & 15;
  const int xq    = col16 & 7;
  const int bh = blockIdx.y, b = bh >> 4, h = bh & 15;
  const int t0 = blockIdx.x * 128;

  const int jr = lane >> 4;   // K/Q staging: row-within-instr 0..3
  const int kg = lane & 15;   // K/Q staging: dest granule (16B units)
  const int vr = lane >> 3;   // V staging: row-within-instr 0..7
  const int vg = lane & 7;    // V staging: dest granule

  _Float16* myK = KS + w * 2048;   // wave staging region: 16 rows x 128
  _Float16* myV = VtS + w * 2048;  // wave staging region: 32 d-rows x 64
  short*    myM = MkS + w * 2048;  // wave mask region: 32 q-rows x 64

  // ---- Q prologue: wave-local glds staging + fragment extraction
  h8 qf[2][4];
#pragma unroll
  for (int t = 0; t < 2; ++t) {
#pragma unroll
    for (int j = 0; j < 4; ++j) {
      int rl = 4 * j + jr;
      int gq = kg ^ (rl & 7);
      size_t go = (size_t)(b * S_LEN + t0 + 64 * t + 16 * w + rl) * NFUSE
                + h * HDIM + gq * 8;
      glds16(QKf + go, myK + j * 512);
    }
    __asm__ volatile("s_waitcnt vmcnt(0)" ::: "memory");
#pragma unroll
    for (int c = 0; c < 4; ++c)
      qf[t][c] = *(const h8*)&myK[col16 * 128 + (((c * 4 + quad) ^ xq) * 8)];
    __asm__ volatile("s_waitcnt lgkmcnt(0)" ::: "memory");  // reads retired
  }

  // ---- per-lane staging offsets (source swizzled; LDS linear), 32-bit
  const _Float16* Kbase = QKf + (size_t)b * S_LEN * NFUSE + 2048;
  const _Float16* Vbase = VT + (size_t)b * HDIM * S_LEN;
  const short*    Mbase = maskb + (size_t)b * S_LEN * S_LEN;
  u32 offK[4], offV[4], offM[4];
#pragma unroll
  for (int j = 0; j < 4; ++j) {
    int rl = 4 * j + jr;
    offK[j] = (u32)(16 * w + rl) * NFUSE + (u32)((kg ^ (rl & 7)) * 8);
    int dl = 32 * w + 8 * j + vr;
    offV[j] = (u32)dl * S_LEN + (u32)((vg ^ (vr & 7)) * 8);
    int mrw = j * 8 + (lane >> 3);                 // 0..31
    int mq  = t0 + 64 * (mrw >> 4) + 16 * w + (mrw & 15);
    offM[j] = (u32)mq * S_LEN + (u32)(((lane & 7) ^ (mrw & 7)) * 8);
  }

  // ---- issue K_0, M_0, V_0 (queue discipline: [K4, M4, V4])
#pragma unroll
  for (int j = 0; j < 4; ++j) glds16(Kbase + offK[j], myK + j * 512);
#pragma unroll
  for (int j = 0; j < 4; ++j) glds16(Mbase + offM[j], myM + j * 512);
#pragma unroll
  for (int j = 0; j < 4; ++j) glds16(Vbase + offV[j], myV + j * 512);
#pragma unroll
  for (int j = 0; j < 4; ++j) {
    offK[j] += 64 * NFUSE; offM[j] += 64; offV[j] += 64;
  }

  f32x4 oacc[2][8];
#pragma unroll
  for (int t = 0; t < 2; ++t)
#pragma unroll
    for (int d = 0; d < 8; ++d) {
      oacc[t][d][0] = 0.f; oacc[t][d][1] = 0.f;
      oacc[t][d][2] = 0.f; oacc[t][d][3] = 0.f;
    }
  float mrow[2] = {-3.0e38f, -3.0e38f};
  float lrow[2] = {0.f, 0.f};

#pragma unroll 1
  for (int it = 0; it < S_LEN / 64; ++it) {
    // ---- B1: K_it arrived on all waves (M_it, V_it still in flight)
    __asm__ volatile("s_waitcnt vmcnt(8)" ::: "memory");
    __builtin_amdgcn_s_barrier();

    // ---- QK^T swapped: sacc[t][nt] = S^T (rows = s-local, cols = q)
    f32x4 sacc[2][4];
#pragma unroll
    for (int t = 0; t < 2; ++t)
#pragma unroll
      for (int nt = 0; nt < 4; ++nt) {
        sacc[t][nt][0] = 0.f; sacc[t][nt][1] = 0.f;
        sacc[t][nt][2] = 0.f; sacc[t][nt][3] = 0.f;
      }
    __builtin_amdgcn_s_setprio(1);
#pragma unroll
    for (int c = 0; c < 4; ++c)
#pragma unroll
      for (int nt = 0; nt < 4; ++nt) {
        h8 k8 = *(const h8*)&KS[(nt * 16 + col16) * 128 + (((c * 4 + quad) ^ xq) * 8)];
#pragma unroll
        for (int t = 0; t < 2; ++t)
          sacc[t][nt] = __builtin_amdgcn_mfma_f32_16x16x32_f16(k8, qf[t][c], sacc[t][nt], 0, 0, 0);
      }
    __builtin_amdgcn_s_setprio(0);

    // ---- M_it + V_it drained; read mask regs (wave-local) before barrier
    __asm__ volatile("s_waitcnt vmcnt(0)" ::: "memory");
    short4v msk[2][4];
#pragma unroll
    for (int t = 0; t < 2; ++t)
#pragma unroll
      for (int nt = 0; nt < 4; ++nt)
        msk[t][nt] = *(const short4v*)
            &myM[(t * 16 + col16) * 64 + (((quad + nt * 4) ^ (xq << 1)) << 2)];
    __asm__ volatile("s_waitcnt lgkmcnt(0)" ::: "memory");  // reads retired
    // ---- B2: K-buf free on all waves
    __builtin_amdgcn_s_barrier();

    if (it + 1 < S_LEN / 64) {   // prefetch K,M_{it+1}, flies under softmax+PV
#pragma unroll
      for (int j = 0; j < 4; ++j) glds16(Kbase + offK[j], myK + j * 512);
#pragma unroll
      for (int j = 0; j < 4; ++j) glds16(Mbase + offM[j], myM + j * 512);
#pragma unroll
      for (int j = 0; j < 4; ++j) { offK[j] += 64 * NFUSE; offM[j] += 64; }
    }

    // ---- online softmax (base-2), per tile; lane owns Q-row col16
#pragma unroll
    for (int t = 0; t < 2; ++t) {
      float vv[4][4];
#pragma unroll
      for (int nt = 0; nt < 4; ++nt)
#pragma unroll
        for (int r = 0; r < 4; ++r)
          vv[nt][r] = sacc[t][nt][r] + bf2f(msk[t][nt][r]);
      float mx = vv[0][0];
#pragma unroll
      for (int nt = 0; nt < 4; ++nt)
#pragma unroll
        for (int r = 0; r < 4; ++r) mx = fmaxf(mx, vv[nt][r]);
      mx = fmaxf(mx, __shfl_xor(mx, 16));
      mx = fmaxf(mx, __shfl_xor(mx, 32));

      float nm = fmaxf(mrow[t], mx);
      if (__all(mx - mrow[t] <= 8.0f)) {
        nm = mrow[t];                       // defer: P bounded by 2^8
      } else {
        float al = fexp2(mrow[t] - nm);
        lrow[t] *= al;
#pragma unroll
        for (int d = 0; d < 8; ++d) {
          oacc[t][d][0] *= al; oacc[t][d][1] *= al;
          oacc[t][d][2] *= al; oacc[t][d][3] *= al;
        }
        mrow[t] = nm;
      }

      float ps = 0.f;
      u32 pk0[4], pk1[4];
#pragma unroll
      for (int nt = 0; nt < 4; ++nt) {
        float p0 = fexp2(vv[nt][0] - nm);
        float p1 = fexp2(vv[nt][1] - nm);
        float p2 = fexp2(vv[nt][2] - nm);
        float p3 = fexp2(vv[nt][3] - nm);
        ps += (p0 + p1) + (p2 + p3);
        pk0[nt] = pkrtz(p0, p1);
        pk1[nt] = pkrtz(p2, p3);
      }
      ps += __shfl_xor(ps, 16);
      ps += __shfl_xor(ps, 32);
      lrow[t] += ps;

      // P store: 4x b64, granule-XOR swizzled
      int pbase = ((t * 4 + w) * 16 + col16) * 64 + (quad & 1) * 4;
#pragma unroll
      for (int nt = 0; nt < 4; ++nt) {
        uint2 pv2; pv2.x = pk0[nt]; pv2.y = pk1[nt];
        *(uint2*)&PsS[pbase + (((2 * nt + (quad >> 1)) ^ xq) * 8)] = pv2;
      }
    }

    // ---- PV swapped: oacc[t][d] += mfma(V^T-frag, P^T-frag)
    __asm__ volatile("s_waitcnt lgkmcnt(0)" ::: "memory");  // P visible in-wave
    h8 pa[2][2];
#pragma unroll
    for (int t = 0; t < 2; ++t) {
      int pb = ((t * 4 + w) * 16 + col16) * 64;
      pa[t][0] = *(const h8*)&PsS[pb + ((quad ^ xq) * 8)];
      pa[t][1] = *(const h8*)&PsS[pb + (((4 + quad) ^ xq) * 8)];
    }
    __builtin_amdgcn_s_setprio(1);
#pragma unroll
    for (int d = 0; d < 8; ++d) {
      int vo = (d * 16 + col16) * 64;
      h8 vb0 = *(const h8*)&VtS[vo + ((quad ^ xq) * 8)];
      h8 vb1 = *(const h8*)&VtS[vo + (((4 + quad) ^ xq) * 8)];
#pragma unroll
      for (int t = 0; t < 2; ++t) {
        oacc[t][d] = __builtin_amdgcn_mfma_f32_16x16x32_f16(vb0, pa[t][0], oacc[t][d], 0, 0, 0);
        oacc[t][d] = __builtin_amdgcn_mfma_f32_16x16x32_f16(vb1, pa[t][1], oacc[t][d], 0, 0, 0);
      }
    }
    __builtin_amdgcn_s_setprio(0);

    // ---- B3: V-buf free on all waves; prefetch V_{it+1}
    __builtin_amdgcn_s_barrier();
    if (it + 1 < S_LEN / 64) {
#pragma unroll
      for (int j = 0; j < 4; ++j) glds16(Vbase + offV[j], myV + j * 512);
#pragma unroll
      for (int j = 0; j < 4; ++j) offV[j] += 64;
    }
  }

  // ---- epilogue: normalize, packed 8B stores, AO fp16 [4096][2048]
#pragma unroll
  for (int t = 0; t < 2; ++t) {
    float inv = 1.0f / lrow[t];
    int q = t0 + 64 * t + 16 * w + col16;
    _Float16* dst = AO + (size_t)(b * S_LEN + q) * EMB + h * HDIM + quad * 4;
#pragma unroll
    for (int d = 0; d < 8; ++d) {
      h4 o4;
#pragma unroll
      for (int r = 0; r < 4; ++r) o4[r] = (_Float16)(oacc[t][d][r] * inv);
      *(h4*)(dst + d * 16) = o4;
    }
  }
}

// ---------------------------------------------------------------------------
extern "C" void kernel_launch(void* const* d_in, const int* in_sizes, int n_in,
                              void* d_out, int out_size, void* d_ws, size_t ws_size,
                              hipStream_t stream) {
  const float* x    = (const float*)d_in[0];
  const float* mask = (const float*)d_in[1];
  const float* W1   = (const float*)d_in[2];
  const float* W2   = (const float*)d_in[3];
  const float* W3   = (const float*)d_in[4];
  float* out = (float*)d_out;

  char* ws = (char*)d_ws;
  size_t off = 0;
  _Float16* xf   = (_Float16*)(ws + off); off += (size_t)4096 * 2048 * 2;    // 16 MiB
  _Float16* Wtf  = (_Float16*)(ws + off); off += (size_t)NFUSE * 2048 * 2;   //  9 MiB
  _Float16* QKf  = (_Float16*)(ws + off); off += (size_t)4096 * NFUSE * 2;   // 18 MiB
  _Float16* VT   = (_Float16*)(ws + off); off += (size_t)2 * 128 * 2048 * 2; //  1 MiB
  _Float16* AOf  = (_Float16*)(ws + off); off += (size_t)4096 * 2048 * 2;    // 16 MiB
  float*    Wkv  = (float*)(ws + off);    off += (size_t)2048 * 256 * 4;     //  2 MiB
  short*    maskb= (short*)(ws + off);    off += (size_t)2 * 2048 * 2048 * 2;// 16 MiB
  _Float16* W3t  = xf;  // alias: xf dead after fused GEMM; W3 transpose runs after

  // 1) prep: Wkv reduce, x->fp16, mask->bf16*log2e, fused W^T fp16
  reduce_w1_kernel<<<2048, 256, 0, stream>>>(W1, Wkv);
  cvt_x_kernel<<<8192, 256, 0, stream>>>(x, xf);
  cvt_mask_kernel<<<8192, 256, 0, stream>>>(mask, maskb);
  transpose_f16_kernel<<<dim3(32, 32), 256, 0, stream>>>(W2, Wtf, 2048, 2048);
  transpose_f16_kernel<<<dim3(4, 32), 256, 0, stream>>>(
      Wkv, Wtf + (size_t)2048 * 2048, 2048, 256);

  // 2) fused projection GEMM: [4096][2304] = x @ [W2 | Wk | Wv], fp16 out,
  //    Q cols pre-scaled by log2e
  gemm_f16<true><<<dim3(NFUSE / 128, 32), 256, 32768, stream>>>(
      xf, Wtf, nullptr, QKf, 4096, NFUSE, 2048, 2048);

  // 3) V^T extraction
  build_vt<<<64, 256, 0, stream>>>((const short*)QKf, (short*)VT);

  // 4) attention
  flash_f16<<<dim3(S_LEN / 128, 2 * NHEAD), 256, 0, stream>>>(
      QKf, VT, maskb, AOf);

  // 5) output projection (fp16 in, f32 out)
  transpose_f16_kernel<<<dim3(32, 32), 256, 0, stream>>>(W3, W3t, 2048, 2048);
  gemm_f16<false><<<dim3(16, 32), 256, 32768, stream>>>(
      AOf, W3t, out, nullptr, 4096, 2048, 2048, 0);
}